// Round 4
// baseline (215.407 us; speedup 1.0000x reference)
//
#include <hip/hip_runtime.h>
#include <math.h>

#define NB   2
#define H0   64
#define W0   64
#define NC   256
#define NPTS 4096
#define NLVL 4
#define NK   49   // (2*3+1)^2

typedef __attribute__((ext_vector_type(8))) short short8;   // 8 bf16 (4 VGPRs)
typedef __attribute__((ext_vector_type(4))) float f32x4;    // MFMA acc

__device__ __forceinline__ short8 as_short8(uint4 u) {
    union { uint4 u; short8 s; } c; c.u = u; return c.s;
}

__device__ __forceinline__ float wave_reduce_sum(float v) {
    for (int m = 32; m >= 1; m >>= 1)
        v += __shfl_xor(v, m, 64);
    return v;
}

// float -> bf16 round-to-nearest-even
__device__ __forceinline__ unsigned short f2bf(float f) {
    unsigned int u = __float_as_uint(f);
    u += 0x7fffu + ((u >> 16) & 1u);
    return (unsigned short)(u >> 16);
}

// jax.image.resize bilinear antialias 2x downsample: separable [1,3,3,1]/8,
// OOB taps dropped + renormalized at edges. One wave per OUTPUT pixel.
__device__ __forceinline__ void down_norm(const float* __restrict__ in,
                                          float* __restrict__ raw_out,
                                          unsigned short* __restrict__ norm_out,
                                          int Hi, int Wi, int wid, int lane) {
    int Ho = Hi >> 1, Wo = Wi >> 1;
    int b = wid / (Ho * Wo);
    int rem = wid - b * (Ho * Wo);
    int yo = rem / Wo, xo = rem - yo * Wo;
    float wy[4], wx[4]; int ty[4], tx[4];
    float sy = 0.f, sx = 0.f;
    for (int j = 0; j < 4; ++j) {
        float w = (j == 0 || j == 3) ? 1.f : 3.f;
        int yi = 2 * yo - 1 + j;
        float wyj = (yi >= 0 && yi < Hi) ? w : 0.f;
        ty[j] = min(max(yi, 0), Hi - 1); wy[j] = wyj; sy += wyj;
        int xi = 2 * xo - 1 + j;
        float wxj = (xi >= 0 && xi < Wi) ? w : 0.f;
        tx[j] = min(max(xi, 0), Wi - 1); wx[j] = wxj; sx += wxj;
    }
    float inv_s = 1.f / (sy * sx);
    float ax = 0.f, ay = 0.f, az = 0.f, aw = 0.f;
    const float4* basep = (const float4*)(in + (size_t)b * Hi * Wi * NC);
    for (int jy = 0; jy < 4; ++jy) {
        if (wy[jy] == 0.f) continue;
        for (int jx = 0; jx < 4; ++jx) {
            float w = wy[jy] * wx[jx];
            if (w == 0.f) continue;
            float4 v = basep[(ty[jy] * Wi + tx[jx]) * (NC / 4) + lane];
            ax += w * v.x; ay += w * v.y; az += w * v.z; aw += w * v.w;
        }
    }
    ax *= inv_s; ay *= inv_s; az *= inv_s; aw *= inv_s;
    float ss = wave_reduce_sum(ax * ax + ay * ay + az * az + aw * aw);
    float inv = 1.f / (sqrtf(ss) + 1e-6f);
    size_t po = ((size_t)b * Ho * Wo + (size_t)yo * Wo + xo) * (NC / 4) + lane;
    if (raw_out) {
        float4 r; r.x = ax; r.y = ay; r.z = az; r.w = aw;
        ((float4*)raw_out)[po] = r;
    }
    ushort4 nn;
    nn.x = f2bf(ax * inv); nn.y = f2bf(ay * inv);
    nn.z = f2bf(az * inv); nn.w = f2bf(aw * inv);
    ((ushort4*)norm_out)[po] = nn;
}

// Level 3 directly from raw1 (level-1 raw, 32x32): two downsample stages
// composed into one 10-tap-per-dim filter, per-stage edge renorm composed exactly.
__device__ __forceinline__ void down3_composed(const float* __restrict__ raw1,
                                               unsigned short* __restrict__ norm_out,
                                               int wid, int lane) {
    int b = wid / 64;
    int rem = wid - b * 64;
    int yo = rem >> 3, xo = rem & 7;
    float Wt[2][10]; int base[2];
    for (int d = 0; d < 2; ++d) {
        int o = d ? xo : yo;
        base[d] = 4 * o - 3;
        float W[10];
        for (int k = 0; k < 10; ++k) W[k] = 0.f;
        float S2 = 0.f;
        for (int j = 0; j < 4; ++j) {
            int yj = 2 * o - 1 + j;
            if (yj < 0 || yj >= 16) continue;
            float wj = (j == 0 || j == 3) ? 1.f : 3.f;
            S2 += wj;
            int yi0 = 2 * yj - 1;
            float wi[4], s1 = 0.f;
            for (int i2 = 0; i2 < 4; ++i2) {
                int yi = yi0 + i2;
                wi[i2] = (yi >= 0 && yi < 32) ? ((i2 == 0 || i2 == 3) ? 1.f : 3.f) : 0.f;
                s1 += wi[i2];
            }
            float sc = wj / s1;
            for (int i2 = 0; i2 < 4; ++i2)
                if (wi[i2] > 0.f) W[yi0 + i2 - base[d]] += wi[i2] * sc;
        }
        float invS = 1.f / S2;
        for (int k = 0; k < 10; ++k) Wt[d][k] = W[k] * invS;
    }
    float ax = 0.f, ay = 0.f, az = 0.f, aw = 0.f;
    const float4* basep = (const float4*)(raw1 + (size_t)b * 32 * 32 * NC);
    for (int ky = 0; ky < 10; ++ky) {
        float wy = Wt[0][ky];
        if (wy == 0.f) continue;
        int yi = base[0] + ky;
        for (int kx = 0; kx < 10; ++kx) {
            float wx = Wt[1][kx];
            if (wx == 0.f) continue;
            int xi = base[1] + kx;
            float4 v = basep[(yi * 32 + xi) * (NC / 4) + lane];
            float wgt = wy * wx;
            ax += wgt * v.x; ay += wgt * v.y; az += wgt * v.z; aw += wgt * v.w;
        }
    }
    float ss = wave_reduce_sum(ax * ax + ay * ay + az * az + aw * aw);
    float inv = 1.f / (sqrtf(ss) + 1e-6f);
    size_t po = ((size_t)b * 64 + yo * 8 + xo) * (NC / 4) + lane;
    ushort4 nn;
    nn.x = f2bf(ax * inv); nn.y = f2bf(ay * inv);
    nn.z = f2bf(az * inv); nn.w = f2bf(aw * inv);
    ((ushort4*)norm_out)[po] = nn;
}

// Fused preprocessing: blocks [0,2048) feat1 (bf16), [2048,4096) norm level0,
// [4096,4608) downsample level1.
__global__ __launch_bounds__(256)
void pre_kernel(const float* __restrict__ fmap1,
                const float* __restrict__ fmap2,
                const float* __restrict__ coords1,
                unsigned short* __restrict__ f1bf,
                unsigned short* __restrict__ f2n0,
                float* __restrict__ raw1,
                unsigned short* __restrict__ f2n1) {
    int blk  = blockIdx.x;
    int wv   = threadIdx.x >> 6;
    int lane = threadIdx.x & 63;
    if (blk < 2048) {
        int pt = blk * 4 + wv;
        int b = pt / NPTS;
        float x = coords1[pt * 2 + 0];
        float y = coords1[pt * 2 + 1];
        int x0 = min(max((int)floorf(x), 0), W0 - 1);
        int y0 = min(max((int)floorf(y), 0), H0 - 1);
        int x1 = min(x0 + 1, W0 - 1);
        int y1 = min(y0 + 1, H0 - 1);
        float wxh = x - (float)x0, wxl = (float)x1 - x;   // clip-first semantics
        float wyh = y - (float)y0, wyl = (float)y1 - y;
        float wa = wxl * wyl, wb = wxl * wyh, wc = wxh * wyl, wd = wxh * wyh;
        const float4* base = (const float4*)(fmap1 + (size_t)b * H0 * W0 * NC);
        float4 Ia = base[(y0 * W0 + x0) * (NC / 4) + lane];
        float4 Ib = base[(y1 * W0 + x0) * (NC / 4) + lane];
        float4 Ic = base[(y0 * W0 + x1) * (NC / 4) + lane];
        float4 Id = base[(y1 * W0 + x1) * (NC / 4) + lane];
        float vx = wa * Ia.x + wb * Ib.x + wc * Ic.x + wd * Id.x;
        float vy = wa * Ia.y + wb * Ib.y + wc * Ic.y + wd * Id.y;
        float vz = wa * Ia.z + wb * Ib.z + wc * Ic.z + wd * Id.z;
        float vw = wa * Ia.w + wb * Ib.w + wc * Ic.w + wd * Id.w;
        float ss = wave_reduce_sum(vx * vx + vy * vy + vz * vz + vw * vw);
        float inv = 1.0f / (sqrtf(ss) + 1e-6f);
        ushort4 o;
        o.x = f2bf(vx * inv); o.y = f2bf(vy * inv);
        o.z = f2bf(vz * inv); o.w = f2bf(vw * inv);
        ((ushort4*)(f1bf + (size_t)pt * NC))[lane] = o;
    } else if (blk < 4096) {
        int p = (blk - 2048) * 4 + wv;
        float4 v = ((const float4*)fmap2)[(size_t)p * (NC / 4) + lane];
        float ss = wave_reduce_sum(v.x * v.x + v.y * v.y + v.z * v.z + v.w * v.w);
        float inv = 1.0f / (sqrtf(ss) + 1e-6f);
        ushort4 nn;
        nn.x = f2bf(v.x * inv); nn.y = f2bf(v.y * inv);
        nn.z = f2bf(v.z * inv); nn.w = f2bf(v.w * inv);
        ((ushort4*)f2n0)[(size_t)p * (NC / 4) + lane] = nn;
    } else {
        int wid = (blk - 4096) * 4 + wv;
        down_norm(fmap2, raw1, f2n1, H0, W0, wid, lane);
    }
}

// Fused small levels: blocks [0,128) level2 from raw1; [128,160) level3.
__global__ __launch_bounds__(256)
void small_kernel(const float* __restrict__ raw1,
                  unsigned short* __restrict__ f2n2,
                  unsigned short* __restrict__ f2n3) {
    int blk  = blockIdx.x;
    int wv   = threadIdx.x >> 6;
    int lane = threadIdx.x & 63;
    if (blk < 128) {
        int wid = blk * 4 + wv;
        down_norm(raw1, (float*)nullptr, f2n2, 32, 32, wid, lane);
    } else {
        int wid = (blk - 128) * 4 + wv;
        down3_composed(raw1, f2n3, wid, lane);
    }
}

// One block per point, wave w = level. MFMA replicated-A dot:
// Per N-tile t (4 tiles x 16 pixels): B[k][n] = f2[pixel n][ch], lane layout
// n=lane&15, k=(lane>>4)*8+j -> lanes {n,n+16,n+32,n+48} read 64 B contiguous
// of pixel n (16-segment coalescing). A: every lane loads feat1 chunk for its
// kgroup only -> all 16 A-rows identical -> every acc register of every lane
// holds dot(feat1, pixel col). 32 MFMAs/wave/level replace ~520 VALU FMA+unpack.
__global__ __launch_bounds__(256)
void corr_kernel(const unsigned short* __restrict__ f1bf,
                 const float* __restrict__ coords2,
                 const unsigned short* __restrict__ f2n0,
                 const unsigned short* __restrict__ f2n1,
                 const unsigned short* __restrict__ f2n2,
                 const unsigned short* __restrict__ f2n3,
                 float* __restrict__ out) {
    __shared__ unsigned short f1s[NC];   // 512 B
    __shared__ float Ds[NLVL][64];
    int pt = blockIdx.x;
    int b  = pt / NPTS;
    int t  = threadIdx.x;
    if (t < 32) ((uint4*)f1s)[t] = ((const uint4*)(f1bf + (size_t)pt * NC))[t];
    __syncthreads();

    int w    = t >> 6;        // level
    int lane = t & 63;
    int Wl = W0 >> w, Hl = H0 >> w;
    float invs = 1.0f / (float)(1 << w);
    float cx = coords2[pt * 2 + 0] * invs;
    float cy = coords2[pt * 2 + 1] * invs;
    int ix = (int)floorf(cx), iy = (int)floorf(cy);

    const unsigned short* f2 = (w == 0) ? f2n0 : (w == 1) ? f2n1 : (w == 2) ? f2n2 : f2n3;

    int kg = lane >> 4;       // k-group (channel chunk) 0..3
    int nn = lane & 15;       // pixel column within tile

    // A fragments: k-chunk s*32 + kg*8 .. +8  ==  uint4 index s*4+kg of f1s.
    short8 a[8];
#pragma unroll
    for (int s = 0; s < 8; ++s)
        a[s] = as_short8(((const uint4*)f1s)[s * 4 + kg]);

#pragma unroll
    for (int tI = 0; tI < 4; ++tI) {
        int p  = tI * 16 + nn;           // grid pixel 0..63
        int jx = p & 7, jy = p >> 3;
        int px = min(max(ix - 3 + jx, 0), Wl - 1);
        int py = min(max(iy - 3 + jy, 0), Hl - 1);
        const uint4* pix = (const uint4*)(f2 + (((size_t)b * Hl + py) * Wl + px) * NC);
        f32x4 acc = {0.f, 0.f, 0.f, 0.f};
#pragma unroll
        for (int s = 0; s < 8; ++s) {
            short8 bf = as_short8(pix[s * 4 + kg]);
            acc = __builtin_amdgcn_mfma_f32_16x16x32_bf16(a[s], bf, acc, 0, 0, 0);
        }
        if (lane < 16) Ds[w][tI * 16 + lane] = acc[0];
    }
    __syncthreads();

    if (lane < NK) {
        int tyk = lane / 7, txk = lane % 7;
        float dx = (float)(txk - 3), dy = (float)(tyk - 3);
        float x = fminf(fmaxf(cx + dx, 0.f), (float)(Wl - 1));
        float y = fminf(fmaxf(cy + dy, 0.f), (float)(Hl - 1));
        int x0 = (int)floorf(x);
        int y0 = (int)floorf(y);
        int x1 = min(x0 + 1, Wl - 1);
        int y1 = min(y0 + 1, Hl - 1);
        float wxh = x - (float)x0, wxl = (float)x1 - x;  // both 0 at exact upper edge
        float wyh = y - (float)y0, wyl = (float)y1 - y;
        int sx0 = min(max(x0 - ix + 3, 0), 7);
        int sx1 = min(max(x1 - ix + 3, 0), 7);
        int sy0 = min(max(y0 - iy + 3, 0), 7);
        int sy1 = min(max(y1 - iy + 3, 0), 7);
        float v = wxl * wyl * Ds[w][sy0 * 8 + sx0]
                + wxl * wyh * Ds[w][sy1 * 8 + sx0]
                + wxh * wyl * Ds[w][sy0 * 8 + sx1]
                + wxh * wyh * Ds[w][sy1 * 8 + sx1];
        out[(size_t)pt * (NLVL * NK) + w * NK + lane] = v;
    }
}

extern "C" void kernel_launch(void* const* d_in, const int* in_sizes, int n_in,
                              void* d_out, int out_size, void* d_ws, size_t ws_size,
                              hipStream_t stream) {
    const float* fmap1   = (const float*)d_in[0];
    const float* fmap2   = (const float*)d_in[1];
    const float* coords1 = (const float*)d_in[2];
    const float* coords2 = (const float*)d_in[3];
    float* out = (float*)d_out;
    float* ws  = (float*)d_ws;

    // workspace layout (float-slot offsets; bf16 arrays cast from float storage)
    float*          raw1 = ws;                               //   524,288 floats
    unsigned short* f1bf = (unsigned short*)(ws + 524288);   // 2,097,152 bf16
    unsigned short* f2n0 = (unsigned short*)(ws + 1572864);  // 2,097,152 bf16
    unsigned short* f2n1 = (unsigned short*)(ws + 2621440);  //   524,288 bf16
    unsigned short* f2n2 = (unsigned short*)(ws + 2883584);  //   131,072 bf16
    unsigned short* f2n3 = (unsigned short*)(ws + 2949120);  //    32,768 bf16
    // total 2,965,504 float slots = 11.3 MiB

    pre_kernel<<<4608, 256, 0, stream>>>(fmap1, fmap2, coords1, f1bf, f2n0, raw1, f2n1);
    small_kernel<<<160, 256, 0, stream>>>(raw1, f2n2, f2n3);
    corr_kernel<<<NB * NPTS, 256, 0, stream>>>(f1bf, coords2, f2n0, f2n1, f2n2, f2n3, out);
}

// Round 5
// 214.996 us; speedup vs baseline: 1.0019x; 1.0019x over previous
//
#include <hip/hip_runtime.h>
#include <math.h>

#define NB   2
#define H0   64
#define W0   64
#define NC   256
#define NPTS 4096
#define NLVL 4
#define NK   49   // (2*3+1)^2

typedef __attribute__((ext_vector_type(8))) short short8;   // 8 bf16 (4 VGPRs)
typedef __attribute__((ext_vector_type(4))) float f32x4;    // MFMA acc

__device__ __forceinline__ short8 as_short8(uint4 u) {
    union { uint4 u; short8 s; } c; c.u = u; return c.s;
}

__device__ __forceinline__ float wave_reduce_sum(float v) {
    for (int m = 32; m >= 1; m >>= 1)
        v += __shfl_xor(v, m, 64);
    return v;
}

// float -> bf16 round-to-nearest-even
__device__ __forceinline__ unsigned short f2bf(float f) {
    unsigned int u = __float_as_uint(f);
    u += 0x7fffu + ((u >> 16) & 1u);
    return (unsigned short)(u >> 16);
}

// jax.image.resize bilinear antialias 2x downsample: separable [1,3,3,1]/8,
// OOB taps dropped + renormalized at edges. One wave per OUTPUT pixel.
__device__ __forceinline__ void down_norm(const float* __restrict__ in,
                                          float* __restrict__ raw_out,
                                          unsigned short* __restrict__ norm_out,
                                          int Hi, int Wi, int wid, int lane) {
    int Ho = Hi >> 1, Wo = Wi >> 1;
    int b = wid / (Ho * Wo);
    int rem = wid - b * (Ho * Wo);
    int yo = rem / Wo, xo = rem - yo * Wo;
    float wy[4], wx[4]; int ty[4], tx[4];
    float sy = 0.f, sx = 0.f;
    for (int j = 0; j < 4; ++j) {
        float w = (j == 0 || j == 3) ? 1.f : 3.f;
        int yi = 2 * yo - 1 + j;
        float wyj = (yi >= 0 && yi < Hi) ? w : 0.f;
        ty[j] = min(max(yi, 0), Hi - 1); wy[j] = wyj; sy += wyj;
        int xi = 2 * xo - 1 + j;
        float wxj = (xi >= 0 && xi < Wi) ? w : 0.f;
        tx[j] = min(max(xi, 0), Wi - 1); wx[j] = wxj; sx += wxj;
    }
    float inv_s = 1.f / (sy * sx);
    float ax = 0.f, ay = 0.f, az = 0.f, aw = 0.f;
    const float4* basep = (const float4*)(in + (size_t)b * Hi * Wi * NC);
    for (int jy = 0; jy < 4; ++jy) {
        if (wy[jy] == 0.f) continue;
        for (int jx = 0; jx < 4; ++jx) {
            float w = wy[jy] * wx[jx];
            if (w == 0.f) continue;
            float4 v = basep[(ty[jy] * Wi + tx[jx]) * (NC / 4) + lane];
            ax += w * v.x; ay += w * v.y; az += w * v.z; aw += w * v.w;
        }
    }
    ax *= inv_s; ay *= inv_s; az *= inv_s; aw *= inv_s;
    float ss = wave_reduce_sum(ax * ax + ay * ay + az * az + aw * aw);
    float inv = 1.f / (sqrtf(ss) + 1e-6f);
    size_t po = ((size_t)b * Ho * Wo + (size_t)yo * Wo + xo) * (NC / 4) + lane;
    if (raw_out) {
        float4 r; r.x = ax; r.y = ay; r.z = az; r.w = aw;
        ((float4*)raw_out)[po] = r;
    }
    ushort4 nn;
    nn.x = f2bf(ax * inv); nn.y = f2bf(ay * inv);
    nn.z = f2bf(az * inv); nn.w = f2bf(aw * inv);
    ((ushort4*)norm_out)[po] = nn;
}

// Level 3 directly from raw1 (level-1 raw, 32x32): two downsample stages
// composed into one 10-tap-per-dim filter, per-stage edge renorm composed exactly.
__device__ __forceinline__ void down3_composed(const float* __restrict__ raw1,
                                               unsigned short* __restrict__ norm_out,
                                               int wid, int lane) {
    int b = wid / 64;
    int rem = wid - b * 64;
    int yo = rem >> 3, xo = rem & 7;
    float Wt[2][10]; int base[2];
    for (int d = 0; d < 2; ++d) {
        int o = d ? xo : yo;
        base[d] = 4 * o - 3;
        float W[10];
        for (int k = 0; k < 10; ++k) W[k] = 0.f;
        float S2 = 0.f;
        for (int j = 0; j < 4; ++j) {
            int yj = 2 * o - 1 + j;
            if (yj < 0 || yj >= 16) continue;
            float wj = (j == 0 || j == 3) ? 1.f : 3.f;
            S2 += wj;
            int yi0 = 2 * yj - 1;
            float wi[4], s1 = 0.f;
            for (int i2 = 0; i2 < 4; ++i2) {
                int yi = yi0 + i2;
                wi[i2] = (yi >= 0 && yi < 32) ? ((i2 == 0 || i2 == 3) ? 1.f : 3.f) : 0.f;
                s1 += wi[i2];
            }
            float sc = wj / s1;
            for (int i2 = 0; i2 < 4; ++i2)
                if (wi[i2] > 0.f) W[yi0 + i2 - base[d]] += wi[i2] * sc;
        }
        float invS = 1.f / S2;
        for (int k = 0; k < 10; ++k) Wt[d][k] = W[k] * invS;
    }
    float ax = 0.f, ay = 0.f, az = 0.f, aw = 0.f;
    const float4* basep = (const float4*)(raw1 + (size_t)b * 32 * 32 * NC);
    for (int ky = 0; ky < 10; ++ky) {
        float wy = Wt[0][ky];
        if (wy == 0.f) continue;
        int yi = base[0] + ky;
        for (int kx = 0; kx < 10; ++kx) {
            float wx = Wt[1][kx];
            if (wx == 0.f) continue;
            int xi = base[1] + kx;
            float4 v = basep[(yi * 32 + xi) * (NC / 4) + lane];
            float wgt = wy * wx;
            ax += wgt * v.x; ay += wgt * v.y; az += wgt * v.z; aw += wgt * v.w;
        }
    }
    float ss = wave_reduce_sum(ax * ax + ay * ay + az * az + aw * aw);
    float inv = 1.f / (sqrtf(ss) + 1e-6f);
    size_t po = ((size_t)b * 64 + yo * 8 + xo) * (NC / 4) + lane;
    ushort4 nn;
    nn.x = f2bf(ax * inv); nn.y = f2bf(ay * inv);
    nn.z = f2bf(az * inv); nn.w = f2bf(aw * inv);
    ((ushort4*)norm_out)[po] = nn;
}

// Fused preprocessing: blocks [0,2048) feat1 (bf16), [2048,4096) norm level0,
// [4096,4608) downsample level1.
__global__ __launch_bounds__(256)
void pre_kernel(const float* __restrict__ fmap1,
                const float* __restrict__ fmap2,
                const float* __restrict__ coords1,
                unsigned short* __restrict__ f1bf,
                unsigned short* __restrict__ f2n0,
                float* __restrict__ raw1,
                unsigned short* __restrict__ f2n1) {
    int blk  = blockIdx.x;
    int wv   = threadIdx.x >> 6;
    int lane = threadIdx.x & 63;
    if (blk < 2048) {
        int pt = blk * 4 + wv;
        int b = pt / NPTS;
        float x = coords1[pt * 2 + 0];
        float y = coords1[pt * 2 + 1];
        int x0 = min(max((int)floorf(x), 0), W0 - 1);
        int y0 = min(max((int)floorf(y), 0), H0 - 1);
        int x1 = min(x0 + 1, W0 - 1);
        int y1 = min(y0 + 1, H0 - 1);
        float wxh = x - (float)x0, wxl = (float)x1 - x;   // clip-first semantics
        float wyh = y - (float)y0, wyl = (float)y1 - y;
        float wa = wxl * wyl, wb = wxl * wyh, wc = wxh * wyl, wd = wxh * wyh;
        const float4* base = (const float4*)(fmap1 + (size_t)b * H0 * W0 * NC);
        float4 Ia = base[(y0 * W0 + x0) * (NC / 4) + lane];
        float4 Ib = base[(y1 * W0 + x0) * (NC / 4) + lane];
        float4 Ic = base[(y0 * W0 + x1) * (NC / 4) + lane];
        float4 Id = base[(y1 * W0 + x1) * (NC / 4) + lane];
        float vx = wa * Ia.x + wb * Ib.x + wc * Ic.x + wd * Id.x;
        float vy = wa * Ia.y + wb * Ib.y + wc * Ic.y + wd * Id.y;
        float vz = wa * Ia.z + wb * Ib.z + wc * Ic.z + wd * Id.z;
        float vw = wa * Ia.w + wb * Ib.w + wc * Ic.w + wd * Id.w;
        float ss = wave_reduce_sum(vx * vx + vy * vy + vz * vz + vw * vw);
        float inv = 1.0f / (sqrtf(ss) + 1e-6f);
        ushort4 o;
        o.x = f2bf(vx * inv); o.y = f2bf(vy * inv);
        o.z = f2bf(vz * inv); o.w = f2bf(vw * inv);
        ((ushort4*)(f1bf + (size_t)pt * NC))[lane] = o;
    } else if (blk < 4096) {
        int p = (blk - 2048) * 4 + wv;
        float4 v = ((const float4*)fmap2)[(size_t)p * (NC / 4) + lane];
        float ss = wave_reduce_sum(v.x * v.x + v.y * v.y + v.z * v.z + v.w * v.w);
        float inv = 1.0f / (sqrtf(ss) + 1e-6f);
        ushort4 nn;
        nn.x = f2bf(v.x * inv); nn.y = f2bf(v.y * inv);
        nn.z = f2bf(v.z * inv); nn.w = f2bf(v.w * inv);
        ((ushort4*)f2n0)[(size_t)p * (NC / 4) + lane] = nn;
    } else {
        int wid = (blk - 4096) * 4 + wv;
        down_norm(fmap2, raw1, f2n1, H0, W0, wid, lane);
    }
}

// Fused small levels: blocks [0,128) level2 from raw1; [128,160) level3.
__global__ __launch_bounds__(256)
void small_kernel(const float* __restrict__ raw1,
                  unsigned short* __restrict__ f2n2,
                  unsigned short* __restrict__ f2n3) {
    int blk  = blockIdx.x;
    int wv   = threadIdx.x >> 6;
    int lane = threadIdx.x & 63;
    if (blk < 128) {
        int wid = blk * 4 + wv;
        down_norm(raw1, (float*)nullptr, f2n2, 32, 32, wid, lane);
    } else {
        int wid = (blk - 128) * 4 + wv;
        down3_composed(raw1, f2n3, wid, lane);
    }
}

// One block per point, wave w = level. MFMA replicated-A dot.
// Round-5 restructure: ALL 32 B-loads are issued up front into buf[4][8]
// (128 VGPRs) so the TA pipe sees 512 in-flight segments per wave; then 4
// INDEPENDENT MFMA chains (s-outer, tile-inner) consume them. launch_bounds
// (256,2) caps VGPR at 256 (est ~210) -> 2 blocks/CU resident keeps the
// address pipe fed across the MFMA phase. Round-4 failure mode (36 VGPRs,
// 1-2 loads in flight, latency-serialized) is thereby removed.
__global__ __launch_bounds__(256, 2)
void corr_kernel(const unsigned short* __restrict__ f1bf,
                 const float* __restrict__ coords2,
                 const unsigned short* __restrict__ f2n0,
                 const unsigned short* __restrict__ f2n1,
                 const unsigned short* __restrict__ f2n2,
                 const unsigned short* __restrict__ f2n3,
                 float* __restrict__ out) {
    __shared__ unsigned short f1s[NC];   // 512 B
    __shared__ float Ds[NLVL][64];
    int pt = blockIdx.x;
    int b  = pt / NPTS;
    int t  = threadIdx.x;
    if (t < 32) ((uint4*)f1s)[t] = ((const uint4*)(f1bf + (size_t)pt * NC))[t];
    __syncthreads();

    int w    = t >> 6;        // level
    int lane = t & 63;
    int Wl = W0 >> w, Hl = H0 >> w;
    float invs = 1.0f / (float)(1 << w);
    float cx = coords2[pt * 2 + 0] * invs;
    float cy = coords2[pt * 2 + 1] * invs;
    int ix = (int)floorf(cx), iy = (int)floorf(cy);

    const unsigned short* f2 = (w == 0) ? f2n0 : (w == 1) ? f2n1 : (w == 2) ? f2n2 : f2n3;

    int kg = lane >> 4;       // k-group (channel chunk) 0..3
    int nn = lane & 15;       // pixel column within tile

    // Per-tile pixel base pointers (lane's pixel for each of the 4 N-tiles).
    const uint4* pix[4];
#pragma unroll
    for (int tI = 0; tI < 4; ++tI) {
        int p  = tI * 16 + nn;           // grid pixel 0..63
        int jx = p & 7, jy = p >> 3;
        int px = min(max(ix - 3 + jx, 0), Wl - 1);
        int py = min(max(iy - 3 + jy, 0), Hl - 1);
        pix[tI] = (const uint4*)(f2 + (((size_t)b * Hl + py) * Wl + px) * NC);
    }

    // Issue ALL loads before any consumer: 32 x uint4 = 512 segments in flight.
    uint4 buf[4][8];
#pragma unroll
    for (int tI = 0; tI < 4; ++tI)
#pragma unroll
        for (int s = 0; s < 8; ++s)
            buf[tI][s] = pix[tI][s * 4 + kg];

    // A fragments: k-chunk s*32 + kg*8 .. +8  ==  uint4 index s*4+kg of f1s.
    short8 a[8];
#pragma unroll
    for (int s = 0; s < 8; ++s)
        a[s] = as_short8(((const uint4*)f1s)[s * 4 + kg]);

    // 4 independent MFMA chains, interleaved (s outer, tile inner).
    f32x4 acc[4];
#pragma unroll
    for (int tI = 0; tI < 4; ++tI) acc[tI] = (f32x4){0.f, 0.f, 0.f, 0.f};
#pragma unroll
    for (int s = 0; s < 8; ++s)
#pragma unroll
        for (int tI = 0; tI < 4; ++tI)
            acc[tI] = __builtin_amdgcn_mfma_f32_16x16x32_bf16(
                a[s], as_short8(buf[tI][s]), acc[tI], 0, 0, 0);

    if (lane < 16) {
#pragma unroll
        for (int tI = 0; tI < 4; ++tI)
            Ds[w][tI * 16 + lane] = acc[tI][0];
    }
    __syncthreads();

    if (lane < NK) {
        int tyk = lane / 7, txk = lane % 7;
        float dx = (float)(txk - 3), dy = (float)(tyk - 3);
        float x = fminf(fmaxf(cx + dx, 0.f), (float)(Wl - 1));
        float y = fminf(fmaxf(cy + dy, 0.f), (float)(Hl - 1));
        int x0 = (int)floorf(x);
        int y0 = (int)floorf(y);
        int x1 = min(x0 + 1, Wl - 1);
        int y1 = min(y0 + 1, Hl - 1);
        float wxh = x - (float)x0, wxl = (float)x1 - x;  // both 0 at exact upper edge
        float wyh = y - (float)y0, wyl = (float)y1 - y;
        int sx0 = min(max(x0 - ix + 3, 0), 7);
        int sx1 = min(max(x1 - ix + 3, 0), 7);
        int sy0 = min(max(y0 - iy + 3, 0), 7);
        int sy1 = min(max(y1 - iy + 3, 0), 7);
        float v = wxl * wyl * Ds[w][sy0 * 8 + sx0]
                + wxl * wyh * Ds[w][sy1 * 8 + sx0]
                + wxh * wyl * Ds[w][sy0 * 8 + sx1]
                + wxh * wyh * Ds[w][sy1 * 8 + sx1];
        out[(size_t)pt * (NLVL * NK) + w * NK + lane] = v;
    }
}

extern "C" void kernel_launch(void* const* d_in, const int* in_sizes, int n_in,
                              void* d_out, int out_size, void* d_ws, size_t ws_size,
                              hipStream_t stream) {
    const float* fmap1   = (const float*)d_in[0];
    const float* fmap2   = (const float*)d_in[1];
    const float* coords1 = (const float*)d_in[2];
    const float* coords2 = (const float*)d_in[3];
    float* out = (float*)d_out;
    float* ws  = (float*)d_ws;

    // workspace layout (float-slot offsets; bf16 arrays cast from float storage)
    float*          raw1 = ws;                               //   524,288 floats
    unsigned short* f1bf = (unsigned short*)(ws + 524288);   // 2,097,152 bf16
    unsigned short* f2n0 = (unsigned short*)(ws + 1572864);  // 2,097,152 bf16
    unsigned short* f2n1 = (unsigned short*)(ws + 2621440);  //   524,288 bf16
    unsigned short* f2n2 = (unsigned short*)(ws + 2883584);  //   131,072 bf16
    unsigned short* f2n3 = (unsigned short*)(ws + 2949120);  //    32,768 bf16
    // total 2,965,504 float slots = 11.3 MiB

    pre_kernel<<<4608, 256, 0, stream>>>(fmap1, fmap2, coords1, f1bf, f2n0, raw1, f2n1);
    small_kernel<<<160, 256, 0, stream>>>(raw1, f2n2, f2n3);
    corr_kernel<<<NB * NPTS, 256, 0, stream>>>(f1bf, coords2, f2n0, f2n1, f2n2, f2n3, out);
}

// Round 6
// 165.563 us; speedup vs baseline: 1.3011x; 1.2986x over previous
//
#include <hip/hip_runtime.h>
#include <math.h>

#define NB   2
#define H0   64
#define W0   64
#define NC   256
#define NPTS 4096
#define NLVL 4
#define NK   49   // (2*3+1)^2

typedef _Float16 half2v __attribute__((ext_vector_type(2)));

union U32H2 { unsigned int u; half2v h; };
__device__ __forceinline__ half2v uh(unsigned int x) { U32H2 c; c.u = x; return c.h; }

__device__ __forceinline__ unsigned short f2h(float f) {
    union { _Float16 h; unsigned short u; } c; c.h = (_Float16)f; return c.u;
}

__device__ __forceinline__ float dot2(half2v a, half2v b, float c) {
#if defined(__has_builtin)
#if __has_builtin(__builtin_amdgcn_fdot2)
    return __builtin_amdgcn_fdot2(a, b, c, false);
#else
    return c + (float)a[0] * (float)b[0] + (float)a[1] * (float)b[1];
#endif
#else
    return c + (float)a[0] * (float)b[0] + (float)a[1] * (float)b[1];
#endif
}

__device__ __forceinline__ float wave_reduce_sum(float v) {
    for (int m = 32; m >= 1; m >>= 1)
        v += __shfl_xor(v, m, 64);
    return v;
}

// One downsample-stage filter expansion: cur (IN entries at curbase) ->
// nxt (2*IN+2 entries at 2*curbase-1). Per-position taps {1,3,3,1}, OOB
// dropped, renormalized per position (matches jax bilinear-antialias 2x).
// All array indices compile-time after unroll (2*i+j).
template<int IN>
__device__ __forceinline__ void expand(const float* cur, int& curbase, int size_in,
                                       float* nxt) {
    const int OUT = 2 * IN + 2;
#pragma unroll
    for (int k = 0; k < OUT; ++k) nxt[k] = 0.f;
#pragma unroll
    for (int i = 0; i < IN; ++i) {
        float wt = cur[i];
        if (wt == 0.f) continue;
        int p = curbase + i;
        float wv[4], S = 0.f;
#pragma unroll
        for (int j = 0; j < 4; ++j) {
            int q = 2 * p - 1 + j;
            float wj = (j == 0 || j == 3) ? 1.f : 3.f;
            wv[j] = (q >= 0 && q < size_in) ? wj : 0.f;
            S += wv[j];
        }
        float sc = wt / S;
#pragma unroll
        for (int j = 0; j < 4; ++j) nxt[2 * i + j] += wv[j] * sc;
    }
    curbase = 2 * curbase - 1;
}

// Fused preprocessing (single launch, all parts independent, inputs only):
//  [0,2048)    feat1 = normalize(bilinear(fmap1, coords1)) -> fp16
//  [2048,4096) level-0 normalize -> fp16
//  [4096,4608) level-1 (4-tap/dim from fmap2) -> fp16
//  [4608,4736) level-2 (composed 10-tap/dim from fmap2) -> fp16
//  [4736,4864) level-3 (composed 22-tap/dim from fmap2), 4-wave coop -> fp16
__global__ __launch_bounds__(256)
void pre_kernel(const float* __restrict__ fmap1,
                const float* __restrict__ fmap2,
                const float* __restrict__ coords1,
                unsigned short* __restrict__ f1h,
                unsigned short* __restrict__ f2n0,
                unsigned short* __restrict__ f2n1,
                unsigned short* __restrict__ f2n2,
                unsigned short* __restrict__ f2n3) {
    __shared__ float4 part[4][64];
    int blk  = blockIdx.x;
    int wv   = threadIdx.x >> 6;
    int lane = threadIdx.x & 63;

    if (blk < 2048) {
        int pt = blk * 4 + wv;
        int b = pt / NPTS;
        float x = coords1[pt * 2 + 0];
        float y = coords1[pt * 2 + 1];
        int x0 = min(max((int)floorf(x), 0), W0 - 1);
        int y0 = min(max((int)floorf(y), 0), H0 - 1);
        int x1 = min(x0 + 1, W0 - 1);
        int y1 = min(y0 + 1, H0 - 1);
        float wxh = x - (float)x0, wxl = (float)x1 - x;   // clip-first semantics
        float wyh = y - (float)y0, wyl = (float)y1 - y;
        float wa = wxl * wyl, wb = wxl * wyh, wc = wxh * wyl, wd = wxh * wyh;
        const float4* base = (const float4*)(fmap1 + (size_t)b * H0 * W0 * NC);
        float4 Ia = base[(y0 * W0 + x0) * (NC / 4) + lane];
        float4 Ib = base[(y1 * W0 + x0) * (NC / 4) + lane];
        float4 Ic = base[(y0 * W0 + x1) * (NC / 4) + lane];
        float4 Id = base[(y1 * W0 + x1) * (NC / 4) + lane];
        float vx = wa * Ia.x + wb * Ib.x + wc * Ic.x + wd * Id.x;
        float vy = wa * Ia.y + wb * Ib.y + wc * Ic.y + wd * Id.y;
        float vz = wa * Ia.z + wb * Ib.z + wc * Ic.z + wd * Id.z;
        float vw = wa * Ia.w + wb * Ib.w + wc * Ic.w + wd * Id.w;
        float ss = wave_reduce_sum(vx * vx + vy * vy + vz * vz + vw * vw);
        float inv = 1.0f / (sqrtf(ss) + 1e-6f);
        ushort4 o;
        o.x = f2h(vx * inv); o.y = f2h(vy * inv);
        o.z = f2h(vz * inv); o.w = f2h(vw * inv);
        ((ushort4*)(f1h + (size_t)pt * NC))[lane] = o;
    } else if (blk < 4096) {
        int p = (blk - 2048) * 4 + wv;
        float4 v = ((const float4*)fmap2)[(size_t)p * (NC / 4) + lane];
        float ss = wave_reduce_sum(v.x * v.x + v.y * v.y + v.z * v.z + v.w * v.w);
        float inv = 1.0f / (sqrtf(ss) + 1e-6f);
        ushort4 nn;
        nn.x = f2h(v.x * inv); nn.y = f2h(v.y * inv);
        nn.z = f2h(v.z * inv); nn.w = f2h(v.w * inv);
        ((ushort4*)f2n0)[(size_t)p * (NC / 4) + lane] = nn;
    } else if (blk < 4608) {
        // level 1: one wave per output pixel (2x32x32), 4x4 taps from fmap2
        int wid = (blk - 4096) * 4 + wv;
        int b = wid >> 10, rem = wid & 1023;
        int yo = rem >> 5, xo = rem & 31;
        float one = 1.f, Wy[6], Wx[6]; int by = yo, bx = xo;
        expand<1>(&one, by, 64, Wy);
        expand<1>(&one, bx, 64, Wx);
        float ax = 0.f, ay = 0.f, az = 0.f, aw = 0.f;
        const float4* basep = (const float4*)(fmap2 + (size_t)b * 64 * 64 * NC);
#pragma unroll
        for (int ky = 0; ky < 4; ++ky) {
            if (Wy[ky] == 0.f) continue;
            int yi = by + ky;
#pragma unroll
            for (int kx = 0; kx < 4; ++kx) {
                if (Wx[kx] == 0.f) continue;
                int xi = bx + kx;
                float wgt = Wy[ky] * Wx[kx];
                float4 v = basep[(yi * 64 + xi) * (NC / 4) + lane];
                ax += wgt * v.x; ay += wgt * v.y; az += wgt * v.z; aw += wgt * v.w;
            }
        }
        float ss = wave_reduce_sum(ax * ax + ay * ay + az * az + aw * aw);
        float inv = 1.f / (sqrtf(ss) + 1e-6f);
        ushort4 nn;
        nn.x = f2h(ax * inv); nn.y = f2h(ay * inv);
        nn.z = f2h(az * inv); nn.w = f2h(aw * inv);
        ((ushort4*)f2n1)[((size_t)b * 1024 + yo * 32 + xo) * (NC / 4) + lane] = nn;
    } else if (blk < 4736) {
        // level 2: one wave per output pixel (2x16x16), composed 10x10 taps
        int wid = (blk - 4608) * 4 + wv;
        int b = wid >> 8, rem = wid & 255;
        int yo = rem >> 4, xo = rem & 15;
        float one = 1.f, t4[6], Wy[10], Wx[10]; int by = yo, bx = xo;
        expand<1>(&one, by, 32, t4); expand<4>(t4, by, 64, Wy);
        expand<1>(&one, bx, 32, t4); expand<4>(t4, bx, 64, Wx);
        float ax = 0.f, ay = 0.f, az = 0.f, aw = 0.f;
        const float4* basep = (const float4*)(fmap2 + (size_t)b * 64 * 64 * NC);
#pragma unroll
        for (int ky = 0; ky < 10; ++ky) {
            if (Wy[ky] == 0.f) continue;
            int yi = by + ky;
#pragma unroll
            for (int kx = 0; kx < 10; ++kx) {
                if (Wx[kx] == 0.f) continue;
                int xi = bx + kx;
                float wgt = Wy[ky] * Wx[kx];
                float4 v = basep[(yi * 64 + xi) * (NC / 4) + lane];
                ax += wgt * v.x; ay += wgt * v.y; az += wgt * v.z; aw += wgt * v.w;
            }
        }
        float ss = wave_reduce_sum(ax * ax + ay * ay + az * az + aw * aw);
        float inv = 1.f / (sqrtf(ss) + 1e-6f);
        ushort4 nn;
        nn.x = f2h(ax * inv); nn.y = f2h(ay * inv);
        nn.z = f2h(az * inv); nn.w = f2h(aw * inv);
        ((ushort4*)f2n2)[((size_t)b * 256 + yo * 16 + xo) * (NC / 4) + lane] = nn;
    } else {
        // level 3: one BLOCK per output pixel (2x8x8), composed 22x22 taps,
        // ky rows split across the 4 waves, LDS reduce.
        int wid = blk - 4736;
        int b = wid >> 6, rem = wid & 63;
        int yo = rem >> 3, xo = rem & 7;
        float one = 1.f, t4[6], t10[10], Wy[22], Wx[22]; int by = yo, bx = xo;
        expand<1>(&one, by, 16, t4); expand<4>(t4, by, 32, t10); expand<10>(t10, by, 64, Wy);
        expand<1>(&one, bx, 16, t4); expand<4>(t4, bx, 32, t10); expand<10>(t10, bx, 64, Wx);
        float ax = 0.f, ay = 0.f, az = 0.f, aw = 0.f;
        const float4* basep = (const float4*)(fmap2 + (size_t)b * 64 * 64 * NC);
#pragma unroll
        for (int ky = 0; ky < 22; ++ky) {
            if ((ky & 3) != wv) continue;
            if (Wy[ky] == 0.f) continue;
            int yi = by + ky;
#pragma unroll
            for (int kx = 0; kx < 22; ++kx) {
                if (Wx[kx] == 0.f) continue;
                int xi = bx + kx;
                float wgt = Wy[ky] * Wx[kx];
                float4 v = basep[(yi * 64 + xi) * (NC / 4) + lane];
                ax += wgt * v.x; ay += wgt * v.y; az += wgt * v.z; aw += wgt * v.w;
            }
        }
        float4 pr; pr.x = ax; pr.y = ay; pr.z = az; pr.w = aw;
        part[wv][lane] = pr;
        __syncthreads();
        if (wv == 0) {
            float4 p0 = part[0][lane], p1 = part[1][lane];
            float4 p2 = part[2][lane], p3 = part[3][lane];
            ax = p0.x + p1.x + p2.x + p3.x;
            ay = p0.y + p1.y + p2.y + p3.y;
            az = p0.z + p1.z + p2.z + p3.z;
            aw = p0.w + p1.w + p2.w + p3.w;
            float ss = wave_reduce_sum(ax * ax + ay * ay + az * az + aw * aw);
            float inv = 1.f / (sqrtf(ss) + 1e-6f);
            ushort4 nn;
            nn.x = f2h(ax * inv); nn.y = f2h(ay * inv);
            nn.z = f2h(az * inv); nn.w = f2h(aw * inv);
            ((ushort4*)f2n3)[((size_t)b * 64 + yo * 8 + xo) * (NC / 4) + lane] = nn;
        }
    }
}

// One block per point, wave w = level. R3 dataflow (VALU dot hides load
// latency — MFMA variants were latency-serialized, see R4/R5 post-mortems),
// but fp16 pyramid + v_dot2_f32_f16: 4 dot2 per 16B chunk instead of
// 8 FMA + 8 unpack bit-ops (4x less VALU). Lane = (pixel slot pq=lane>>2,
// channel group cg=lane&3); quad lanes read 64 B contiguous per load.
__global__ __launch_bounds__(256)
void corr_kernel(const unsigned short* __restrict__ f1h,
                 const float* __restrict__ coords2,
                 const unsigned short* __restrict__ f2n0,
                 const unsigned short* __restrict__ f2n1,
                 const unsigned short* __restrict__ f2n2,
                 const unsigned short* __restrict__ f2n3,
                 float* __restrict__ out) {
    __shared__ unsigned short f1s[NC];   // 512 B fp16
    __shared__ float Ds[NLVL][64];
    int pt = blockIdx.x;
    int b  = pt / NPTS;
    int t  = threadIdx.x;
    if (t < 32) ((uint4*)f1s)[t] = ((const uint4*)(f1h + (size_t)pt * NC))[t];
    __syncthreads();

    int w    = t >> 6;        // level
    int lane = t & 63;
    int Wl = W0 >> w, Hl = H0 >> w;
    float invs = 1.0f / (float)(1 << w);
    float cx = coords2[pt * 2 + 0] * invs;
    float cy = coords2[pt * 2 + 1] * invs;
    int ix = (int)floorf(cx), iy = (int)floorf(cy);

    const unsigned short* f2 = (w == 0) ? f2n0 : (w == 1) ? f2n1 : (w == 2) ? f2n2 : f2n3;

    int cg = lane & 3;        // channel chunk group
    int pq = lane >> 2;       // pixel slot (0..15)

    // feat1 fragments: uint4 chunk s*4+cg covers channels (s*4+cg)*8..+8.
    uint4 a4[8];
#pragma unroll
    for (int s = 0; s < 8; ++s)
        a4[s] = ((const uint4*)f1s)[s * 4 + cg];

#pragma unroll
    for (int i = 0; i < 4; ++i) {
        int p  = i * 16 + pq;            // grid pixel 0..63
        int jx = p & 7, jy = p >> 3;
        int px = min(max(ix - 3 + jx, 0), Wl - 1);
        int py = min(max(iy - 3 + jy, 0), Hl - 1);
        const uint4* pix = (const uint4*)(f2 + (((size_t)b * Hl + py) * Wl + px) * NC);
        float acc = 0.f;
#pragma unroll
        for (int s = 0; s < 8; ++s) {
            uint4 u = pix[s * 4 + cg];   // quad lanes cover 64 B contiguous
            uint4 av = a4[s];
            acc = dot2(uh(av.x), uh(u.x), acc);
            acc = dot2(uh(av.y), uh(u.y), acc);
            acc = dot2(uh(av.z), uh(u.z), acc);
            acc = dot2(uh(av.w), uh(u.w), acc);
        }
        acc += __shfl_xor(acc, 1, 64);
        acc += __shfl_xor(acc, 2, 64);
        if (cg == 0) Ds[w][p] = acc;
    }
    __syncthreads();

    if (lane < NK) {
        int tyk = lane / 7, txk = lane % 7;
        float dx = (float)(txk - 3), dy = (float)(tyk - 3);
        float x = fminf(fmaxf(cx + dx, 0.f), (float)(Wl - 1));
        float y = fminf(fmaxf(cy + dy, 0.f), (float)(Hl - 1));
        int x0 = (int)floorf(x);
        int y0 = (int)floorf(y);
        int x1 = min(x0 + 1, Wl - 1);
        int y1 = min(y0 + 1, Hl - 1);
        float wxh = x - (float)x0, wxl = (float)x1 - x;  // both 0 at exact upper edge
        float wyh = y - (float)y0, wyl = (float)y1 - y;
        int sx0 = min(max(x0 - ix + 3, 0), 7);
        int sx1 = min(max(x1 - ix + 3, 0), 7);
        int sy0 = min(max(y0 - iy + 3, 0), 7);
        int sy1 = min(max(y1 - iy + 3, 0), 7);
        float v = wxl * wyl * Ds[w][sy0 * 8 + sx0]
                + wxl * wyh * Ds[w][sy1 * 8 + sx0]
                + wxh * wyl * Ds[w][sy0 * 8 + sx1]
                + wxh * wyh * Ds[w][sy1 * 8 + sx1];
        out[(size_t)pt * (NLVL * NK) + w * NK + lane] = v;
    }
}

extern "C" void kernel_launch(void* const* d_in, const int* in_sizes, int n_in,
                              void* d_out, int out_size, void* d_ws, size_t ws_size,
                              hipStream_t stream) {
    const float* fmap1   = (const float*)d_in[0];
    const float* fmap2   = (const float*)d_in[1];
    const float* coords1 = (const float*)d_in[2];
    const float* coords2 = (const float*)d_in[3];
    float* out = (float*)d_out;
    float* ws  = (float*)d_ws;

    // workspace layout (float-slot offsets; fp16 arrays cast from float storage)
    unsigned short* f1h  = (unsigned short*)(ws);            // 2,097,152 fp16
    unsigned short* f2n0 = (unsigned short*)(ws + 1048576);  // 2,097,152 fp16
    unsigned short* f2n1 = (unsigned short*)(ws + 2097152);  //   524,288 fp16
    unsigned short* f2n2 = (unsigned short*)(ws + 2359296);  //   131,072 fp16
    unsigned short* f2n3 = (unsigned short*)(ws + 2424832);  //    32,768 fp16
    // total 2,441,216 float slots = 9.3 MiB

    pre_kernel<<<4864, 256, 0, stream>>>(fmap1, fmap2, coords1,
                                         f1h, f2n0, f2n1, f2n2, f2n3);
    corr_kernel<<<NB * NPTS, 256, 0, stream>>>(f1h, coords2, f2n0, f2n1, f2n2, f2n3, out);
}

// Round 7
// 153.366 us; speedup vs baseline: 1.4045x; 1.0795x over previous
//
#include <hip/hip_runtime.h>
#include <math.h>

#define NB   2
#define H0   64
#define W0   64
#define NC   256
#define NPTS 4096
#define NLVL 4
#define NK   49   // (2*3+1)^2

typedef _Float16 half2v __attribute__((ext_vector_type(2)));

union U32H2 { unsigned int u; half2v h; };
__device__ __forceinline__ half2v uh(unsigned int x) { U32H2 c; c.u = x; return c.h; }

__device__ __forceinline__ unsigned short f2h(float f) {
    union { _Float16 h; unsigned short u; } c; c.h = (_Float16)f; return c.u;
}

__device__ __forceinline__ float dot2(half2v a, half2v b, float c) {
#if defined(__has_builtin)
#if __has_builtin(__builtin_amdgcn_fdot2)
    return __builtin_amdgcn_fdot2(a, b, c, false);
#else
    return c + (float)a[0] * (float)b[0] + (float)a[1] * (float)b[1];
#endif
#else
    return c + (float)a[0] * (float)b[0] + (float)a[1] * (float)b[1];
#endif
}

__device__ __forceinline__ float wave_reduce_sum(float v) {
    for (int m = 32; m >= 1; m >>= 1)
        v += __shfl_xor(v, m, 64);
    return v;
}

// One downsample-stage filter expansion: cur (IN entries at curbase) ->
// nxt (2*IN+2 entries at 2*curbase-1). Per-position taps {1,3,3,1}, OOB
// dropped, renormalized per position (matches jax bilinear-antialias 2x).
template<int IN>
__device__ __forceinline__ void expand(const float* cur, int& curbase, int size_in,
                                       float* nxt) {
    const int OUT = 2 * IN + 2;
#pragma unroll
    for (int k = 0; k < OUT; ++k) nxt[k] = 0.f;
#pragma unroll
    for (int i = 0; i < IN; ++i) {
        float wt = cur[i];
        if (wt == 0.f) continue;
        int p = curbase + i;
        float wv[4], S = 0.f;
#pragma unroll
        for (int j = 0; j < 4; ++j) {
            int q = 2 * p - 1 + j;
            float wj = (j == 0 || j == 3) ? 1.f : 3.f;
            wv[j] = (q >= 0 && q < size_in) ? wj : 0.f;
            S += wv[j];
        }
        float sc = wt / S;
#pragma unroll
        for (int j = 0; j < 4; ++j) nxt[2 * i + j] += wv[j] * sc;
    }
    curbase = 2 * curbase - 1;
}

// Fused preprocessing (single launch, all parts independent, inputs only):
//  [0,2048)    feat1 = normalize(bilinear(fmap1, coords1)) -> fp16
//  [2048,4096) level-0 normalize -> fp16
//  [4096,4608) level-1 (4-tap/dim from fmap2) -> fp16
//  [4608,4736) level-2 (composed 10-tap/dim from fmap2) -> fp16
//  [4736,4864) level-3 (composed 22-tap/dim from fmap2), 4-wave coop -> fp16
__global__ __launch_bounds__(256)
void pre_kernel(const float* __restrict__ fmap1,
                const float* __restrict__ fmap2,
                const float* __restrict__ coords1,
                unsigned short* __restrict__ f1h,
                unsigned short* __restrict__ f2n0,
                unsigned short* __restrict__ f2n1,
                unsigned short* __restrict__ f2n2,
                unsigned short* __restrict__ f2n3) {
    __shared__ float4 part[4][64];
    int blk  = blockIdx.x;
    int wv   = threadIdx.x >> 6;
    int lane = threadIdx.x & 63;

    if (blk < 2048) {
        int pt = blk * 4 + wv;
        int b = pt / NPTS;
        float x = coords1[pt * 2 + 0];
        float y = coords1[pt * 2 + 1];
        int x0 = min(max((int)floorf(x), 0), W0 - 1);
        int y0 = min(max((int)floorf(y), 0), H0 - 1);
        int x1 = min(x0 + 1, W0 - 1);
        int y1 = min(y0 + 1, H0 - 1);
        float wxh = x - (float)x0, wxl = (float)x1 - x;   // clip-first semantics
        float wyh = y - (float)y0, wyl = (float)y1 - y;
        float wa = wxl * wyl, wb = wxl * wyh, wc = wxh * wyl, wd = wxh * wyh;
        const float4* base = (const float4*)(fmap1 + (size_t)b * H0 * W0 * NC);
        float4 Ia = base[(y0 * W0 + x0) * (NC / 4) + lane];
        float4 Ib = base[(y1 * W0 + x0) * (NC / 4) + lane];
        float4 Ic = base[(y0 * W0 + x1) * (NC / 4) + lane];
        float4 Id = base[(y1 * W0 + x1) * (NC / 4) + lane];
        float vx = wa * Ia.x + wb * Ib.x + wc * Ic.x + wd * Id.x;
        float vy = wa * Ia.y + wb * Ib.y + wc * Ic.y + wd * Id.y;
        float vz = wa * Ia.z + wb * Ib.z + wc * Ic.z + wd * Id.z;
        float vw = wa * Ia.w + wb * Ib.w + wc * Ic.w + wd * Id.w;
        float ss = wave_reduce_sum(vx * vx + vy * vy + vz * vz + vw * vw);
        float inv = 1.0f / (sqrtf(ss) + 1e-6f);
        ushort4 o;
        o.x = f2h(vx * inv); o.y = f2h(vy * inv);
        o.z = f2h(vz * inv); o.w = f2h(vw * inv);
        ((ushort4*)(f1h + (size_t)pt * NC))[lane] = o;
    } else if (blk < 4096) {
        int p = (blk - 2048) * 4 + wv;
        float4 v = ((const float4*)fmap2)[(size_t)p * (NC / 4) + lane];
        float ss = wave_reduce_sum(v.x * v.x + v.y * v.y + v.z * v.z + v.w * v.w);
        float inv = 1.0f / (sqrtf(ss) + 1e-6f);
        ushort4 nn;
        nn.x = f2h(v.x * inv); nn.y = f2h(v.y * inv);
        nn.z = f2h(v.z * inv); nn.w = f2h(v.w * inv);
        ((ushort4*)f2n0)[(size_t)p * (NC / 4) + lane] = nn;
    } else if (blk < 4608) {
        // level 1: one wave per output pixel (2x32x32), 4x4 taps from fmap2
        int wid = (blk - 4096) * 4 + wv;
        int b = wid >> 10, rem = wid & 1023;
        int yo = rem >> 5, xo = rem & 31;
        float one = 1.f, Wy[6], Wx[6]; int by = yo, bx = xo;
        expand<1>(&one, by, 64, Wy);
        expand<1>(&one, bx, 64, Wx);
        float ax = 0.f, ay = 0.f, az = 0.f, aw = 0.f;
        const float4* basep = (const float4*)(fmap2 + (size_t)b * 64 * 64 * NC);
#pragma unroll
        for (int ky = 0; ky < 4; ++ky) {
            if (Wy[ky] == 0.f) continue;
            int yi = by + ky;
#pragma unroll
            for (int kx = 0; kx < 4; ++kx) {
                if (Wx[kx] == 0.f) continue;
                int xi = bx + kx;
                float wgt = Wy[ky] * Wx[kx];
                float4 v = basep[(yi * 64 + xi) * (NC / 4) + lane];
                ax += wgt * v.x; ay += wgt * v.y; az += wgt * v.z; aw += wgt * v.w;
            }
        }
        float ss = wave_reduce_sum(ax * ax + ay * ay + az * az + aw * aw);
        float inv = 1.f / (sqrtf(ss) + 1e-6f);
        ushort4 nn;
        nn.x = f2h(ax * inv); nn.y = f2h(ay * inv);
        nn.z = f2h(az * inv); nn.w = f2h(aw * inv);
        ((ushort4*)f2n1)[((size_t)b * 1024 + yo * 32 + xo) * (NC / 4) + lane] = nn;
    } else if (blk < 4736) {
        // level 2: one wave per output pixel (2x16x16), composed 10x10 taps
        int wid = (blk - 4608) * 4 + wv;
        int b = wid >> 8, rem = wid & 255;
        int yo = rem >> 4, xo = rem & 15;
        float one = 1.f, t4[6], Wy[10], Wx[10]; int by = yo, bx = xo;
        expand<1>(&one, by, 32, t4); expand<4>(t4, by, 64, Wy);
        expand<1>(&one, bx, 32, t4); expand<4>(t4, bx, 64, Wx);
        float ax = 0.f, ay = 0.f, az = 0.f, aw = 0.f;
        const float4* basep = (const float4*)(fmap2 + (size_t)b * 64 * 64 * NC);
#pragma unroll
        for (int ky = 0; ky < 10; ++ky) {
            if (Wy[ky] == 0.f) continue;
            int yi = by + ky;
#pragma unroll
            for (int kx = 0; kx < 10; ++kx) {
                if (Wx[kx] == 0.f) continue;
                int xi = bx + kx;
                float wgt = Wy[ky] * Wx[kx];
                float4 v = basep[(yi * 64 + xi) * (NC / 4) + lane];
                ax += wgt * v.x; ay += wgt * v.y; az += wgt * v.z; aw += wgt * v.w;
            }
        }
        float ss = wave_reduce_sum(ax * ax + ay * ay + az * az + aw * aw);
        float inv = 1.f / (sqrtf(ss) + 1e-6f);
        ushort4 nn;
        nn.x = f2h(ax * inv); nn.y = f2h(ay * inv);
        nn.z = f2h(az * inv); nn.w = f2h(aw * inv);
        ((ushort4*)f2n2)[((size_t)b * 256 + yo * 16 + xo) * (NC / 4) + lane] = nn;
    } else {
        // level 3: one BLOCK per output pixel (2x8x8), composed 22x22 taps,
        // ky rows split across the 4 waves, LDS reduce.
        int wid = blk - 4736;
        int b = wid >> 6, rem = wid & 63;
        int yo = rem >> 3, xo = rem & 7;
        float one = 1.f, t4[6], t10[10], Wy[22], Wx[22]; int by = yo, bx = xo;
        expand<1>(&one, by, 16, t4); expand<4>(t4, by, 32, t10); expand<10>(t10, by, 64, Wy);
        expand<1>(&one, bx, 16, t4); expand<4>(t4, bx, 32, t10); expand<10>(t10, bx, 64, Wx);
        float ax = 0.f, ay = 0.f, az = 0.f, aw = 0.f;
        const float4* basep = (const float4*)(fmap2 + (size_t)b * 64 * 64 * NC);
#pragma unroll
        for (int ky = 0; ky < 22; ++ky) {
            if ((ky & 3) != wv) continue;
            if (Wy[ky] == 0.f) continue;
            int yi = by + ky;
#pragma unroll
            for (int kx = 0; kx < 22; ++kx) {
                if (Wx[kx] == 0.f) continue;
                int xi = bx + kx;
                float wgt = Wy[ky] * Wx[kx];
                float4 v = basep[(yi * 64 + xi) * (NC / 4) + lane];
                ax += wgt * v.x; ay += wgt * v.y; az += wgt * v.z; aw += wgt * v.w;
            }
        }
        float4 pr; pr.x = ax; pr.y = ay; pr.z = az; pr.w = aw;
        part[wv][lane] = pr;
        __syncthreads();
        if (wv == 0) {
            float4 p0 = part[0][lane], p1 = part[1][lane];
            float4 p2 = part[2][lane], p3 = part[3][lane];
            ax = p0.x + p1.x + p2.x + p3.x;
            ay = p0.y + p1.y + p2.y + p3.y;
            az = p0.z + p1.z + p2.z + p3.z;
            aw = p0.w + p1.w + p2.w + p3.w;
            float ss = wave_reduce_sum(ax * ax + ay * ay + az * az + aw * aw);
            float inv = 1.f / (sqrtf(ss) + 1e-6f);
            ushort4 nn;
            nn.x = f2h(ax * inv); nn.y = f2h(ay * inv);
            nn.z = f2h(az * inv); nn.w = f2h(aw * inv);
            ((ushort4*)f2n3)[((size_t)b * 64 + yo * 8 + xo) * (NC / 4) + lane] = nn;
        }
    }
}

// One block per point, wave w = level. fp16 dot2 dataflow (R6) + R7 changes:
//  (1) feat1 fragments loaded DIRECTLY from global (address s*4+cg is
//      pq-independent -> 4 lines/load, L2-hot) — removes LDS stage + barrier.
//  (2) software-pipelined double buffer: tile i+1's 8 loads (32 VGPRs)
//      issue before tile i's compute — small enough stage to avoid the R5
//      pressure-driven load sinking (128-VGPR staging collapsed to 2 in
//      flight). VGPR_Count is the tell: >=100 means the pipeline held.
//  (3) 4 independent dot2 accumulator chains per tile.
__global__ __launch_bounds__(256)
void corr_kernel(const unsigned short* __restrict__ f1h,
                 const float* __restrict__ coords2,
                 const unsigned short* __restrict__ f2n0,
                 const unsigned short* __restrict__ f2n1,
                 const unsigned short* __restrict__ f2n2,
                 const unsigned short* __restrict__ f2n3,
                 float* __restrict__ out) {
    __shared__ float Ds[NLVL][64];
    int pt = blockIdx.x;
    int b  = pt / NPTS;
    int t  = threadIdx.x;

    int w    = t >> 6;        // level
    int lane = t & 63;
    int Wl = W0 >> w, Hl = H0 >> w;
    float invs = 1.0f / (float)(1 << w);
    float cx = coords2[pt * 2 + 0] * invs;
    float cy = coords2[pt * 2 + 1] * invs;
    int ix = (int)floorf(cx), iy = (int)floorf(cy);

    const unsigned short* f2 = (w == 0) ? f2n0 : (w == 1) ? f2n1 : (w == 2) ? f2n2 : f2n3;

    int cg = lane & 3;        // channel chunk group
    int pq = lane >> 2;       // pixel slot (0..15)

    // Per-tile pixel base pointers.
    const uint4* pixp[4];
#pragma unroll
    for (int i = 0; i < 4; ++i) {
        int p  = i * 16 + pq;            // grid pixel 0..63
        int jx = p & 7, jy = p >> 3;
        int px = min(max(ix - 3 + jx, 0), Wl - 1);
        int py = min(max(iy - 3 + jy, 0), Hl - 1);
        pixp[i] = (const uint4*)(f2 + (((size_t)b * Hl + py) * Wl + px) * NC);
    }

    // feat1 fragments direct from global: chunk s*4+cg (pq-independent).
    const uint4* f1p = (const uint4*)(f1h + (size_t)pt * NC);
    uint4 a4[8];
#pragma unroll
    for (int s = 0; s < 8; ++s) a4[s] = f1p[s * 4 + cg];

    // Software pipeline: prologue loads tile 0; each iteration prefetches
    // tile i+1 then computes tile i.
    uint4 buf[2][8];
#pragma unroll
    for (int s = 0; s < 8; ++s) buf[0][s] = pixp[0][s * 4 + cg];

#pragma unroll
    for (int i = 0; i < 4; ++i) {
        if (i < 3) {
#pragma unroll
            for (int s = 0; s < 8; ++s)
                buf[(i + 1) & 1][s] = pixp[i + 1][s * 4 + cg];
        }
        float ac0 = 0.f, ac1 = 0.f, ac2 = 0.f, ac3 = 0.f;
#pragma unroll
        for (int s = 0; s < 8; ++s) {
            uint4 u = buf[i & 1][s];
            uint4 av = a4[s];
            ac0 = dot2(uh(av.x), uh(u.x), ac0);
            ac1 = dot2(uh(av.y), uh(u.y), ac1);
            ac2 = dot2(uh(av.z), uh(u.z), ac2);
            ac3 = dot2(uh(av.w), uh(u.w), ac3);
        }
        float acc = (ac0 + ac1) + (ac2 + ac3);
        acc += __shfl_xor(acc, 1, 64);
        acc += __shfl_xor(acc, 2, 64);
        if (cg == 0) Ds[w][i * 16 + pq] = acc;
    }
    __syncthreads();

    if (lane < NK) {
        int tyk = lane / 7, txk = lane % 7;
        float dx = (float)(txk - 3), dy = (float)(tyk - 3);
        float x = fminf(fmaxf(cx + dx, 0.f), (float)(Wl - 1));
        float y = fminf(fmaxf(cy + dy, 0.f), (float)(Hl - 1));
        int x0 = (int)floorf(x);
        int y0 = (int)floorf(y);
        int x1 = min(x0 + 1, Wl - 1);
        int y1 = min(y0 + 1, Hl - 1);
        float wxh = x - (float)x0, wxl = (float)x1 - x;  // both 0 at exact upper edge
        float wyh = y - (float)y0, wyl = (float)y1 - y;
        int sx0 = min(max(x0 - ix + 3, 0), 7);
        int sx1 = min(max(x1 - ix + 3, 0), 7);
        int sy0 = min(max(y0 - iy + 3, 0), 7);
        int sy1 = min(max(y1 - iy + 3, 0), 7);
        float v = wxl * wyl * Ds[w][sy0 * 8 + sx0]
                + wxl * wyh * Ds[w][sy1 * 8 + sx0]
                + wxh * wyl * Ds[w][sy0 * 8 + sx1]
                + wxh * wyh * Ds[w][sy1 * 8 + sx1];
        out[(size_t)pt * (NLVL * NK) + w * NK + lane] = v;
    }
}

extern "C" void kernel_launch(void* const* d_in, const int* in_sizes, int n_in,
                              void* d_out, int out_size, void* d_ws, size_t ws_size,
                              hipStream_t stream) {
    const float* fmap1   = (const float*)d_in[0];
    const float* fmap2   = (const float*)d_in[1];
    const float* coords1 = (const float*)d_in[2];
    const float* coords2 = (const float*)d_in[3];
    float* out = (float*)d_out;
    float* ws  = (float*)d_ws;

    // workspace layout (float-slot offsets; fp16 arrays cast from float storage)
    unsigned short* f1h  = (unsigned short*)(ws);            // 2,097,152 fp16
    unsigned short* f2n0 = (unsigned short*)(ws + 1048576);  // 2,097,152 fp16
    unsigned short* f2n1 = (unsigned short*)(ws + 2097152);  //   524,288 fp16
    unsigned short* f2n2 = (unsigned short*)(ws + 2359296);  //   131,072 fp16
    unsigned short* f2n3 = (unsigned short*)(ws + 2424832);  //    32,768 fp16
    // total 2,441,216 float slots = 9.3 MiB

    pre_kernel<<<4864, 256, 0, stream>>>(fmap1, fmap2, coords1,
                                         f1h, f2n0, f2n1, f2n2, f2n3);
    corr_kernel<<<NB * NPTS, 256, 0, stream>>>(f1h, coords2, f2n0, f2n1, f2n2, f2n3, out);
}

// Round 8
// 151.088 us; speedup vs baseline: 1.4257x; 1.0151x over previous
//
#include <hip/hip_runtime.h>
#include <math.h>

#define NB   2
#define H0   64
#define W0   64
#define NC   256
#define NPTS 4096
#define NLVL 4
#define NK   49   // (2*3+1)^2

typedef _Float16 half2v __attribute__((ext_vector_type(2)));

union U32H2 { unsigned int u; half2v h; };
__device__ __forceinline__ half2v uh(unsigned int x) { U32H2 c; c.u = x; return c.h; }

__device__ __forceinline__ unsigned short f2h(float f) {
    union { _Float16 h; unsigned short u; } c; c.h = (_Float16)f; return c.u;
}

__device__ __forceinline__ float dot2(half2v a, half2v b, float c) {
#if defined(__has_builtin)
#if __has_builtin(__builtin_amdgcn_fdot2)
    return __builtin_amdgcn_fdot2(a, b, c, false);
#else
    return c + (float)a[0] * (float)b[0] + (float)a[1] * (float)b[1];
#endif
#else
    return c + (float)a[0] * (float)b[0] + (float)a[1] * (float)b[1];
#endif
}

__device__ __forceinline__ float wave_reduce_sum(float v) {
    for (int m = 32; m >= 1; m >>= 1)
        v += __shfl_xor(v, m, 64);
    return v;
}

// jax.image.resize bilinear antialias 2x downsample: separable [1,3,3,1]/8,
// OOB taps dropped + renormalized at edges. One wave per OUTPUT pixel.
// Writes raw fp32 (optional, for cascade) and fp16 normalized output.
__device__ __forceinline__ void down_norm(const float* __restrict__ in,
                                          float* __restrict__ raw_out,
                                          unsigned short* __restrict__ norm_out,
                                          int Hi, int Wi, int wid, int lane) {
    int Ho = Hi >> 1, Wo = Wi >> 1;
    int b = wid / (Ho * Wo);
    int rem = wid - b * (Ho * Wo);
    int yo = rem / Wo, xo = rem - yo * Wo;
    float wy[4], wx[4]; int ty[4], tx[4];
    float sy = 0.f, sx = 0.f;
    for (int j = 0; j < 4; ++j) {
        float w = (j == 0 || j == 3) ? 1.f : 3.f;
        int yi = 2 * yo - 1 + j;
        float wyj = (yi >= 0 && yi < Hi) ? w : 0.f;
        ty[j] = min(max(yi, 0), Hi - 1); wy[j] = wyj; sy += wyj;
        int xi = 2 * xo - 1 + j;
        float wxj = (xi >= 0 && xi < Wi) ? w : 0.f;
        tx[j] = min(max(xi, 0), Wi - 1); wx[j] = wxj; sx += wxj;
    }
    float inv_s = 1.f / (sy * sx);
    float ax = 0.f, ay = 0.f, az = 0.f, aw = 0.f;
    const float4* basep = (const float4*)(in + (size_t)b * Hi * Wi * NC);
    for (int jy = 0; jy < 4; ++jy) {
        if (wy[jy] == 0.f) continue;
        for (int jx = 0; jx < 4; ++jx) {
            float w = wy[jy] * wx[jx];
            if (w == 0.f) continue;
            float4 v = basep[(ty[jy] * Wi + tx[jx]) * (NC / 4) + lane];
            ax += w * v.x; ay += w * v.y; az += w * v.z; aw += w * v.w;
        }
    }
    ax *= inv_s; ay *= inv_s; az *= inv_s; aw *= inv_s;
    float ss = wave_reduce_sum(ax * ax + ay * ay + az * az + aw * aw);
    float inv = 1.f / (sqrtf(ss) + 1e-6f);
    size_t po = ((size_t)b * Ho * Wo + (size_t)yo * Wo + xo) * (NC / 4) + lane;
    if (raw_out) {
        float4 r; r.x = ax; r.y = ay; r.z = az; r.w = aw;
        ((float4*)raw_out)[po] = r;
    }
    ushort4 nn;
    nn.x = f2h(ax * inv); nn.y = f2h(ay * inv);
    nn.z = f2h(az * inv); nn.w = f2h(aw * inv);
    ((ushort4*)norm_out)[po] = nn;
}

// Level 3 directly from raw1 (level-1 raw, 32x32): two downsample stages
// composed into one 10-tap-per-dim filter, per-stage edge renorm composed
// exactly (validated in R3/R5).
__device__ __forceinline__ void down3_composed(const float* __restrict__ raw1,
                                               unsigned short* __restrict__ norm_out,
                                               int wid, int lane) {
    int b = wid / 64;
    int rem = wid - b * 64;
    int yo = rem >> 3, xo = rem & 7;
    float Wt[2][10]; int base[2];
    for (int d = 0; d < 2; ++d) {
        int o = d ? xo : yo;
        base[d] = 4 * o - 3;
        float W[10];
        for (int k = 0; k < 10; ++k) W[k] = 0.f;
        float S2 = 0.f;
        for (int j = 0; j < 4; ++j) {
            int yj = 2 * o - 1 + j;
            if (yj < 0 || yj >= 16) continue;
            float wj = (j == 0 || j == 3) ? 1.f : 3.f;
            S2 += wj;
            int yi0 = 2 * yj - 1;
            float wi[4], s1 = 0.f;
            for (int i2 = 0; i2 < 4; ++i2) {
                int yi = yi0 + i2;
                wi[i2] = (yi >= 0 && yi < 32) ? ((i2 == 0 || i2 == 3) ? 1.f : 3.f) : 0.f;
                s1 += wi[i2];
            }
            float sc = wj / s1;
            for (int i2 = 0; i2 < 4; ++i2)
                if (wi[i2] > 0.f) W[yi0 + i2 - base[d]] += wi[i2] * sc;
        }
        float invS = 1.f / S2;
        for (int k = 0; k < 10; ++k) Wt[d][k] = W[k] * invS;
    }
    float ax = 0.f, ay = 0.f, az = 0.f, aw = 0.f;
    const float4* basep = (const float4*)(raw1 + (size_t)b * 32 * 32 * NC);
    for (int ky = 0; ky < 10; ++ky) {
        float wy = Wt[0][ky];
        if (wy == 0.f) continue;
        int yi = base[0] + ky;
        for (int kx = 0; kx < 10; ++kx) {
            float wx = Wt[1][kx];
            if (wx == 0.f) continue;
            int xi = base[1] + kx;
            float4 v = basep[(yi * 32 + xi) * (NC / 4) + lane];
            float wgt = wy * wx;
            ax += wgt * v.x; ay += wgt * v.y; az += wgt * v.z; aw += wgt * v.w;
        }
    }
    float ss = wave_reduce_sum(ax * ax + ay * ay + az * az + aw * aw);
    float inv = 1.f / (sqrtf(ss) + 1e-6f);
    size_t po = ((size_t)b * 64 + yo * 8 + xo) * (NC / 4) + lane;
    ushort4 nn;
    nn.x = f2h(ax * inv); nn.y = f2h(ay * inv);
    nn.z = f2h(az * inv); nn.w = f2h(aw * inv);
    ((ushort4*)norm_out)[po] = nn;
}

// Fused preprocessing, streaming-only (tail-heavy composed filters moved to
// small_kernel — the R6/R7 fused version spent ~113 MB of L2/L3 traffic in a
// 256-block tail and ran at 12% occupancy for 50 us):
//  [0,2048)    feat1 = normalize(bilinear(fmap1, coords1)) -> fp16
//  [2048,4096) level-0 normalize -> fp16
//  [4096,4608) level-1 downsample (raw fp32 + fp16 norm)
__global__ __launch_bounds__(256)
void pre_kernel(const float* __restrict__ fmap1,
                const float* __restrict__ fmap2,
                const float* __restrict__ coords1,
                unsigned short* __restrict__ f1h,
                unsigned short* __restrict__ f2n0,
                float* __restrict__ raw1,
                unsigned short* __restrict__ f2n1) {
    int blk  = blockIdx.x;
    int wv   = threadIdx.x >> 6;
    int lane = threadIdx.x & 63;
    if (blk < 2048) {
        int pt = blk * 4 + wv;
        int b = pt / NPTS;
        float x = coords1[pt * 2 + 0];
        float y = coords1[pt * 2 + 1];
        int x0 = min(max((int)floorf(x), 0), W0 - 1);
        int y0 = min(max((int)floorf(y), 0), H0 - 1);
        int x1 = min(x0 + 1, W0 - 1);
        int y1 = min(y0 + 1, H0 - 1);
        float wxh = x - (float)x0, wxl = (float)x1 - x;   // clip-first semantics
        float wyh = y - (float)y0, wyl = (float)y1 - y;
        float wa = wxl * wyl, wb = wxl * wyh, wc = wxh * wyl, wd = wxh * wyh;
        const float4* base = (const float4*)(fmap1 + (size_t)b * H0 * W0 * NC);
        float4 Ia = base[(y0 * W0 + x0) * (NC / 4) + lane];
        float4 Ib = base[(y1 * W0 + x0) * (NC / 4) + lane];
        float4 Ic = base[(y0 * W0 + x1) * (NC / 4) + lane];
        float4 Id = base[(y1 * W0 + x1) * (NC / 4) + lane];
        float vx = wa * Ia.x + wb * Ib.x + wc * Ic.x + wd * Id.x;
        float vy = wa * Ia.y + wb * Ib.y + wc * Ic.y + wd * Id.y;
        float vz = wa * Ia.z + wb * Ib.z + wc * Ic.z + wd * Id.z;
        float vw = wa * Ia.w + wb * Ib.w + wc * Ic.w + wd * Id.w;
        float ss = wave_reduce_sum(vx * vx + vy * vy + vz * vz + vw * vw);
        float inv = 1.0f / (sqrtf(ss) + 1e-6f);
        ushort4 o;
        o.x = f2h(vx * inv); o.y = f2h(vy * inv);
        o.z = f2h(vz * inv); o.w = f2h(vw * inv);
        ((ushort4*)(f1h + (size_t)pt * NC))[lane] = o;
    } else if (blk < 4096) {
        int p = (blk - 2048) * 4 + wv;
        float4 v = ((const float4*)fmap2)[(size_t)p * (NC / 4) + lane];
        float ss = wave_reduce_sum(v.x * v.x + v.y * v.y + v.z * v.z + v.w * v.w);
        float inv = 1.0f / (sqrtf(ss) + 1e-6f);
        ushort4 nn;
        nn.x = f2h(v.x * inv); nn.y = f2h(v.y * inv);
        nn.z = f2h(v.z * inv); nn.w = f2h(v.w * inv);
        ((ushort4*)f2n0)[(size_t)p * (NC / 4) + lane] = nn;
    } else {
        int wid = (blk - 4096) * 4 + wv;
        down_norm(fmap2, raw1, f2n1, H0, W0, wid, lane);
    }
}

// Small levels from raw1 (cascade — 21 MB of L2 traffic vs 113 MB composed):
// blocks [0,128) level2 (4x4 taps); [128,160) level3 (composed 10x10).
__global__ __launch_bounds__(256)
void small_kernel(const float* __restrict__ raw1,
                  unsigned short* __restrict__ f2n2,
                  unsigned short* __restrict__ f2n3) {
    int blk  = blockIdx.x;
    int wv   = threadIdx.x >> 6;
    int lane = threadIdx.x & 63;
    if (blk < 128) {
        int wid = blk * 4 + wv;
        down_norm(raw1, (float*)nullptr, f2n2, 32, 32, wid, lane);
    } else {
        int wid = (blk - 128) * 4 + wv;
        down3_composed(raw1, f2n3, wid, lane);
    }
}

// One block per point, wave w = level. fp16 dot2 dataflow + R7 pipeline
// (direct-global feat1 fragments, 2-stage double buffer, 4 acc chains) —
// unchanged from R7 (corr dropped below 50 us there).
__global__ __launch_bounds__(256)
void corr_kernel(const unsigned short* __restrict__ f1h,
                 const float* __restrict__ coords2,
                 const unsigned short* __restrict__ f2n0,
                 const unsigned short* __restrict__ f2n1,
                 const unsigned short* __restrict__ f2n2,
                 const unsigned short* __restrict__ f2n3,
                 float* __restrict__ out) {
    __shared__ float Ds[NLVL][64];
    int pt = blockIdx.x;
    int b  = pt / NPTS;
    int t  = threadIdx.x;

    int w    = t >> 6;        // level
    int lane = t & 63;
    int Wl = W0 >> w, Hl = H0 >> w;
    float invs = 1.0f / (float)(1 << w);
    float cx = coords2[pt * 2 + 0] * invs;
    float cy = coords2[pt * 2 + 1] * invs;
    int ix = (int)floorf(cx), iy = (int)floorf(cy);

    const unsigned short* f2 = (w == 0) ? f2n0 : (w == 1) ? f2n1 : (w == 2) ? f2n2 : f2n3;

    int cg = lane & 3;        // channel chunk group
    int pq = lane >> 2;       // pixel slot (0..15)

    // Per-tile pixel base pointers.
    const uint4* pixp[4];
#pragma unroll
    for (int i = 0; i < 4; ++i) {
        int p  = i * 16 + pq;            // grid pixel 0..63
        int jx = p & 7, jy = p >> 3;
        int px = min(max(ix - 3 + jx, 0), Wl - 1);
        int py = min(max(iy - 3 + jy, 0), Hl - 1);
        pixp[i] = (const uint4*)(f2 + (((size_t)b * Hl + py) * Wl + px) * NC);
    }

    // feat1 fragments direct from global: chunk s*4+cg (pq-independent).
    const uint4* f1p = (const uint4*)(f1h + (size_t)pt * NC);
    uint4 a4[8];
#pragma unroll
    for (int s = 0; s < 8; ++s) a4[s] = f1p[s * 4 + cg];

    // Software pipeline: prologue loads tile 0; each iteration prefetches
    // tile i+1 then computes tile i.
    uint4 buf[2][8];
#pragma unroll
    for (int s = 0; s < 8; ++s) buf[0][s] = pixp[0][s * 4 + cg];

#pragma unroll
    for (int i = 0; i < 4; ++i) {
        if (i < 3) {
#pragma unroll
            for (int s = 0; s < 8; ++s)
                buf[(i + 1) & 1][s] = pixp[i + 1][s * 4 + cg];
        }
        float ac0 = 0.f, ac1 = 0.f, ac2 = 0.f, ac3 = 0.f;
#pragma unroll
        for (int s = 0; s < 8; ++s) {
            uint4 u = buf[i & 1][s];
            uint4 av = a4[s];
            ac0 = dot2(uh(av.x), uh(u.x), ac0);
            ac1 = dot2(uh(av.y), uh(u.y), ac1);
            ac2 = dot2(uh(av.z), uh(u.z), ac2);
            ac3 = dot2(uh(av.w), uh(u.w), ac3);
        }
        float acc = (ac0 + ac1) + (ac2 + ac3);
        acc += __shfl_xor(acc, 1, 64);
        acc += __shfl_xor(acc, 2, 64);
        if (cg == 0) Ds[w][i * 16 + pq] = acc;
    }
    __syncthreads();

    if (lane < NK) {
        int tyk = lane / 7, txk = lane % 7;
        float dx = (float)(txk - 3), dy = (float)(tyk - 3);
        float x = fminf(fmaxf(cx + dx, 0.f), (float)(Wl - 1));
        float y = fminf(fmaxf(cy + dy, 0.f), (float)(Hl - 1));
        int x0 = (int)floorf(x);
        int y0 = (int)floorf(y);
        int x1 = min(x0 + 1, Wl - 1);
        int y1 = min(y0 + 1, Hl - 1);
        float wxh = x - (float)x0, wxl = (float)x1 - x;  // both 0 at exact upper edge
        float wyh = y - (float)y0, wyl = (float)y1 - y;
        int sx0 = min(max(x0 - ix + 3, 0), 7);
        int sx1 = min(max(x1 - ix + 3, 0), 7);
        int sy0 = min(max(y0 - iy + 3, 0), 7);
        int sy1 = min(max(y1 - iy + 3, 0), 7);
        float v = wxl * wyl * Ds[w][sy0 * 8 + sx0]
                + wxl * wyh * Ds[w][sy1 * 8 + sx0]
                + wxh * wyl * Ds[w][sy0 * 8 + sx1]
                + wxh * wyh * Ds[w][sy1 * 8 + sx1];
        out[(size_t)pt * (NLVL * NK) + w * NK + lane] = v;
    }
}

extern "C" void kernel_launch(void* const* d_in, const int* in_sizes, int n_in,
                              void* d_out, int out_size, void* d_ws, size_t ws_size,
                              hipStream_t stream) {
    const float* fmap1   = (const float*)d_in[0];
    const float* fmap2   = (const float*)d_in[1];
    const float* coords1 = (const float*)d_in[2];
    const float* coords2 = (const float*)d_in[3];
    float* out = (float*)d_out;
    float* ws  = (float*)d_ws;

    // workspace layout (float-slot offsets; fp16 arrays cast from float storage)
    float*          raw1 = ws;                               //   524,288 floats
    unsigned short* f1h  = (unsigned short*)(ws + 524288);   // 2,097,152 fp16
    unsigned short* f2n0 = (unsigned short*)(ws + 1572864);  // 2,097,152 fp16
    unsigned short* f2n1 = (unsigned short*)(ws + 2621440);  //   524,288 fp16
    unsigned short* f2n2 = (unsigned short*)(ws + 2883584);  //   131,072 fp16
    unsigned short* f2n3 = (unsigned short*)(ws + 2949120);  //    32,768 fp16
    // total 2,965,504 float slots = 11.3 MiB

    pre_kernel<<<4608, 256, 0, stream>>>(fmap1, fmap2, coords1, f1h, f2n0, raw1, f2n1);
    small_kernel<<<160, 256, 0, stream>>>(raw1, f2n2, f2n3);
    corr_kernel<<<NB * NPTS, 256, 0, stream>>>(f1h, coords2, f2n0, f2n1, f2n2, f2n3, out);
}

// Round 9
// 132.759 us; speedup vs baseline: 1.6225x; 1.1381x over previous
//
#include <hip/hip_runtime.h>
#include <math.h>

#define NB   2
#define H0   64
#define W0   64
#define NC   256
#define NPTS 4096
#define NLVL 4
#define NK   49   // (2*3+1)^2

__device__ __forceinline__ float wave_reduce_sum(float v) {
    for (int m = 32; m >= 1; m >>= 1)
        v += __shfl_xor(v, m, 64);
    return v;
}

__device__ __forceinline__ float wave_reduce_max(float v) {
    for (int m = 32; m >= 1; m >>= 1)
        v = fmaxf(v, __shfl_xor(v, m, 64));
    return v;
}

// packed signed-int8 dot4 with int32 accumulate
__device__ __forceinline__ int dot4i(unsigned a, unsigned b, int c) {
#if defined(__has_builtin)
#if __has_builtin(__builtin_amdgcn_sdot4)
    return __builtin_amdgcn_sdot4((int)a, (int)b, c, false);
#else
    c += (((int)(a << 24)) >> 24) * (((int)(b << 24)) >> 24);
    c += (((int)(a << 16)) >> 24) * (((int)(b << 16)) >> 24);
    c += (((int)(a <<  8)) >> 24) * (((int)(b <<  8)) >> 24);
    c += (((int)a) >> 24)         * (((int)b) >> 24);
    return c;
#endif
#else
    c += (((int)(a << 24)) >> 24) * (((int)(b << 24)) >> 24);
    c += (((int)(a << 16)) >> 24) * (((int)(b << 16)) >> 24);
    c += (((int)(a <<  8)) >> 24) * (((int)(b <<  8)) >> 24);
    c += (((int)a) >> 24)         * (((int)b) >> 24);
    return c;
#endif
}

// Quantize a wave-held unit vector (4 comps/lane) to int8 with per-vector
// symmetric scale; store packed dword/lane + scale_inv. Exact int dot later:
// dot = (int32 sum) * sa * sb.
__device__ __forceinline__ void quant_store(float nx, float ny, float nz, float nw,
                                            unsigned char* __restrict__ qout,
                                            size_t pixIdx,
                                            float* __restrict__ sout, int lane) {
    float m = fmaxf(fmaxf(fabsf(nx), fabsf(ny)), fmaxf(fabsf(nz), fabsf(nw)));
    float M = wave_reduce_max(m);
    float s = (M > 0.f) ? 127.f / M : 0.f;
    int qx = __float2int_rn(nx * s), qy = __float2int_rn(ny * s);
    int qz = __float2int_rn(nz * s), qw = __float2int_rn(nw * s);
    unsigned p = (qx & 0xff) | ((qy & 0xff) << 8) | ((qz & 0xff) << 16) | ((qw & 0xff) << 24);
    ((unsigned*)(qout + pixIdx * NC))[lane] = p;
    if (lane == 0) sout[pixIdx] = (M > 0.f) ? M / 127.f : 0.f;
}

// jax.image.resize bilinear antialias 2x downsample: separable [1,3,3,1]/8,
// OOB taps dropped + renormalized at edges. One wave per OUTPUT pixel.
// Writes raw fp32 (optional, for cascade) and int8-quantized normalized output.
__device__ __forceinline__ void down_norm(const float* __restrict__ in,
                                          float* __restrict__ raw_out,
                                          unsigned char* __restrict__ qout,
                                          float* __restrict__ sout,
                                          int Hi, int Wi, int wid, int lane) {
    int Ho = Hi >> 1, Wo = Wi >> 1;
    int b = wid / (Ho * Wo);
    int rem = wid - b * (Ho * Wo);
    int yo = rem / Wo, xo = rem - yo * Wo;
    float wy[4], wx[4]; int ty[4], tx[4];
    float sy = 0.f, sx = 0.f;
    for (int j = 0; j < 4; ++j) {
        float w = (j == 0 || j == 3) ? 1.f : 3.f;
        int yi = 2 * yo - 1 + j;
        float wyj = (yi >= 0 && yi < Hi) ? w : 0.f;
        ty[j] = min(max(yi, 0), Hi - 1); wy[j] = wyj; sy += wyj;
        int xi = 2 * xo - 1 + j;
        float wxj = (xi >= 0 && xi < Wi) ? w : 0.f;
        tx[j] = min(max(xi, 0), Wi - 1); wx[j] = wxj; sx += wxj;
    }
    float inv_s = 1.f / (sy * sx);
    float ax = 0.f, ay = 0.f, az = 0.f, aw = 0.f;
    const float4* basep = (const float4*)(in + (size_t)b * Hi * Wi * NC);
    for (int jy = 0; jy < 4; ++jy) {
        if (wy[jy] == 0.f) continue;
        for (int jx = 0; jx < 4; ++jx) {
            float w = wy[jy] * wx[jx];
            if (w == 0.f) continue;
            float4 v = basep[(ty[jy] * Wi + tx[jx]) * (NC / 4) + lane];
            ax += w * v.x; ay += w * v.y; az += w * v.z; aw += w * v.w;
        }
    }
    ax *= inv_s; ay *= inv_s; az *= inv_s; aw *= inv_s;
    float ss = wave_reduce_sum(ax * ax + ay * ay + az * az + aw * aw);
    float inv = 1.f / (sqrtf(ss) + 1e-6f);
    size_t po = (size_t)b * Ho * Wo + (size_t)yo * Wo + xo;
    if (raw_out) {
        float4 r; r.x = ax; r.y = ay; r.z = az; r.w = aw;
        ((float4*)raw_out)[po * (NC / 4) + lane] = r;
    }
    quant_store(ax * inv, ay * inv, az * inv, aw * inv, qout, po, sout, lane);
}

// Level 3 directly from raw1 (level-1 raw, 32x32): two downsample stages
// composed into one 10-tap-per-dim filter, per-stage edge renorm composed
// exactly (validated R3/R5/R8).
__device__ __forceinline__ void down3_composed(const float* __restrict__ raw1,
                                               unsigned char* __restrict__ qout,
                                               float* __restrict__ sout,
                                               int wid, int lane) {
    int b = wid / 64;
    int rem = wid - b * 64;
    int yo = rem >> 3, xo = rem & 7;
    float Wt[2][10]; int base[2];
    for (int d = 0; d < 2; ++d) {
        int o = d ? xo : yo;
        base[d] = 4 * o - 3;
        float W[10];
        for (int k = 0; k < 10; ++k) W[k] = 0.f;
        float S2 = 0.f;
        for (int j = 0; j < 4; ++j) {
            int yj = 2 * o - 1 + j;
            if (yj < 0 || yj >= 16) continue;
            float wj = (j == 0 || j == 3) ? 1.f : 3.f;
            S2 += wj;
            int yi0 = 2 * yj - 1;
            float wi[4], s1 = 0.f;
            for (int i2 = 0; i2 < 4; ++i2) {
                int yi = yi0 + i2;
                wi[i2] = (yi >= 0 && yi < 32) ? ((i2 == 0 || i2 == 3) ? 1.f : 3.f) : 0.f;
                s1 += wi[i2];
            }
            float sc = wj / s1;
            for (int i2 = 0; i2 < 4; ++i2)
                if (wi[i2] > 0.f) W[yi0 + i2 - base[d]] += wi[i2] * sc;
        }
        float invS = 1.f / S2;
        for (int k = 0; k < 10; ++k) Wt[d][k] = W[k] * invS;
    }
    float ax = 0.f, ay = 0.f, az = 0.f, aw = 0.f;
    const float4* basep = (const float4*)(raw1 + (size_t)b * 32 * 32 * NC);
    for (int ky = 0; ky < 10; ++ky) {
        float wy = Wt[0][ky];
        if (wy == 0.f) continue;
        int yi = base[0] + ky;
        for (int kx = 0; kx < 10; ++kx) {
            float wx = Wt[1][kx];
            if (wx == 0.f) continue;
            int xi = base[1] + kx;
            float4 v = basep[(yi * 32 + xi) * (NC / 4) + lane];
            float wgt = wy * wx;
            ax += wgt * v.x; ay += wgt * v.y; az += wgt * v.z; aw += wgt * v.w;
        }
    }
    float ss = wave_reduce_sum(ax * ax + ay * ay + az * az + aw * aw);
    float inv = 1.f / (sqrtf(ss) + 1e-6f);
    size_t po = (size_t)b * 64 + yo * 8 + xo;
    quant_store(ax * inv, ay * inv, az * inv, aw * inv, qout, po, sout, lane);
}

// Fused preprocessing (streaming):
//  [0,2048)    feat1 = normalize(bilinear(fmap1, coords1)) -> int8+scale
//  [2048,4096) level-0 normalize -> int8+scale
//  [4096,4608) level-1 downsample (raw fp32 + int8 norm)
__global__ __launch_bounds__(256)
void pre_kernel(const float* __restrict__ fmap1,
                const float* __restrict__ fmap2,
                const float* __restrict__ coords1,
                unsigned char* __restrict__ f1q, float* __restrict__ fsc,
                unsigned char* __restrict__ q0,  float* __restrict__ s0,
                float* __restrict__ raw1,
                unsigned char* __restrict__ q1,  float* __restrict__ s1) {
    int blk  = blockIdx.x;
    int wv   = threadIdx.x >> 6;
    int lane = threadIdx.x & 63;
    if (blk < 2048) {
        int pt = blk * 4 + wv;
        int b = pt / NPTS;
        float x = coords1[pt * 2 + 0];
        float y = coords1[pt * 2 + 1];
        int x0 = min(max((int)floorf(x), 0), W0 - 1);
        int y0 = min(max((int)floorf(y), 0), H0 - 1);
        int x1 = min(x0 + 1, W0 - 1);
        int y1 = min(y0 + 1, H0 - 1);
        float wxh = x - (float)x0, wxl = (float)x1 - x;   // clip-first semantics
        float wyh = y - (float)y0, wyl = (float)y1 - y;
        float wa = wxl * wyl, wb = wxl * wyh, wc = wxh * wyl, wd = wxh * wyh;
        const float4* base = (const float4*)(fmap1 + (size_t)b * H0 * W0 * NC);
        float4 Ia = base[(y0 * W0 + x0) * (NC / 4) + lane];
        float4 Ib = base[(y1 * W0 + x0) * (NC / 4) + lane];
        float4 Ic = base[(y0 * W0 + x1) * (NC / 4) + lane];
        float4 Id = base[(y1 * W0 + x1) * (NC / 4) + lane];
        float vx = wa * Ia.x + wb * Ib.x + wc * Ic.x + wd * Id.x;
        float vy = wa * Ia.y + wb * Ib.y + wc * Ic.y + wd * Id.y;
        float vz = wa * Ia.z + wb * Ib.z + wc * Ic.z + wd * Id.z;
        float vw = wa * Ia.w + wb * Ib.w + wc * Ic.w + wd * Id.w;
        float ss = wave_reduce_sum(vx * vx + vy * vy + vz * vz + vw * vw);
        float inv = 1.0f / (sqrtf(ss) + 1e-6f);
        quant_store(vx * inv, vy * inv, vz * inv, vw * inv, f1q, pt, fsc, lane);
    } else if (blk < 4096) {
        int p = (blk - 2048) * 4 + wv;
        float4 v = ((const float4*)fmap2)[(size_t)p * (NC / 4) + lane];
        float ss = wave_reduce_sum(v.x * v.x + v.y * v.y + v.z * v.z + v.w * v.w);
        float inv = 1.0f / (sqrtf(ss) + 1e-6f);
        quant_store(v.x * inv, v.y * inv, v.z * inv, v.w * inv, q0, p, s0, lane);
    } else {
        int wid = (blk - 4096) * 4 + wv;
        down_norm(fmap2, raw1, q1, s1, H0, W0, wid, lane);
    }
}

// Small levels from raw1 (cascade): blocks [0,128) level2; [128,160) level3.
__global__ __launch_bounds__(256)
void small_kernel(const float* __restrict__ raw1,
                  unsigned char* __restrict__ q2, float* __restrict__ s2,
                  unsigned char* __restrict__ q3, float* __restrict__ s3) {
    int blk  = blockIdx.x;
    int wv   = threadIdx.x >> 6;
    int lane = threadIdx.x & 63;
    if (blk < 128) {
        int wid = blk * 4 + wv;
        down_norm(raw1, (float*)nullptr, q2, s2, 32, 32, wid, lane);
    } else {
        int wid = (blk - 128) * 4 + wv;
        down3_composed(raw1, q3, s3, wid, lane);
    }
}

__device__ __forceinline__ int tile_dot(const uint4* buf, const uint4* a4) {
    int ac = 0;
#pragma unroll
    for (int s = 0; s < 4; ++s) {
        uint4 u = buf[s], av = a4[s];
        ac = dot4i(av.x, u.x, ac);
        ac = dot4i(av.y, u.y, ac);
        ac = dot4i(av.z, u.z, ac);
        ac = dot4i(av.w, u.w, ac);
    }
    return ac;
}

// One block per point, wave w = level. int8 pyramid: pixel = 256 B; quad of
// lanes (cg=lane&3) covers 64 B contiguous per load -> 4 loads/tile (half of
// fp16's TA segments). Integer dot4 accumulate (exact), final scale sa*sb.
// R7 pipeline kept: 2-tile-deep double buffer, direct-global feat1 fragments.
__global__ __launch_bounds__(256)
void corr_kernel(const unsigned char* __restrict__ f1q,
                 const float* __restrict__ fsc,
                 const float* __restrict__ coords2,
                 const unsigned char* __restrict__ q0, const float* __restrict__ s0,
                 const unsigned char* __restrict__ q1, const float* __restrict__ s1,
                 const unsigned char* __restrict__ q2, const float* __restrict__ s2,
                 const unsigned char* __restrict__ q3, const float* __restrict__ s3,
                 float* __restrict__ out) {
    __shared__ float Ds[NLVL][64];
    int pt = blockIdx.x;
    int b  = pt / NPTS;
    int t  = threadIdx.x;

    int w    = t >> 6;        // level
    int lane = t & 63;
    int Wl = W0 >> w, Hl = H0 >> w;
    float invs = 1.0f / (float)(1 << w);
    float cx = coords2[pt * 2 + 0] * invs;
    float cy = coords2[pt * 2 + 1] * invs;
    int ix = (int)floorf(cx), iy = (int)floorf(cy);

    const unsigned char* f2q = (w == 0) ? q0 : (w == 1) ? q1 : (w == 2) ? q2 : q3;
    const float*         f2s = (w == 0) ? s0 : (w == 1) ? s1 : (w == 2) ? s2 : s3;

    int cg = lane & 3;        // channel chunk group
    int pq = lane >> 2;       // pixel slot (0..15)

    // Per-tile pixel index + base pointer + scale.
    const uint4* pixp[4];
    float sb[4];
#pragma unroll
    for (int i = 0; i < 4; ++i) {
        int p  = i * 16 + pq;            // grid pixel 0..63
        int jx = p & 7, jy = p >> 3;
        int px = min(max(ix - 3 + jx, 0), Wl - 1);
        int py = min(max(iy - 3 + jy, 0), Hl - 1);
        int idx = (b * Hl + py) * Wl + px;
        pixp[i] = (const uint4*)(f2q + (size_t)idx * NC);
        sb[i]   = f2s[idx];
    }
    float sa = fsc[pt];

    // feat1 int8 fragments direct from global (pq-independent address).
    const uint4* f1p = (const uint4*)(f1q + (size_t)pt * NC);
    uint4 a4[4];
#pragma unroll
    for (int s = 0; s < 4; ++s) a4[s] = f1p[s * 4 + cg];

    // Two-tile-deep software pipeline.
    uint4 b0[4], b1[4];
#pragma unroll
    for (int s = 0; s < 4; ++s) b0[s] = pixp[0][s * 4 + cg];
#pragma unroll
    for (int s = 0; s < 4; ++s) b1[s] = pixp[1][s * 4 + cg];

    int ac;
#define EMIT(i, ac_) {                                                   \
        int r = (ac_);                                                   \
        r += __shfl_xor(r, 1, 64);                                       \
        r += __shfl_xor(r, 2, 64);                                       \
        if (cg == 0) Ds[w][(i) * 16 + pq] = (float)r * sa * sb[i];       \
    }
    ac = tile_dot(b0, a4);
#pragma unroll
    for (int s = 0; s < 4; ++s) b0[s] = pixp[2][s * 4 + cg];
    EMIT(0, ac);
    ac = tile_dot(b1, a4);
#pragma unroll
    for (int s = 0; s < 4; ++s) b1[s] = pixp[3][s * 4 + cg];
    EMIT(1, ac);
    ac = tile_dot(b0, a4);
    EMIT(2, ac);
    ac = tile_dot(b1, a4);
    EMIT(3, ac);
#undef EMIT
    __syncthreads();

    if (lane < NK) {
        int tyk = lane / 7, txk = lane % 7;
        float dx = (float)(txk - 3), dy = (float)(tyk - 3);
        float x = fminf(fmaxf(cx + dx, 0.f), (float)(Wl - 1));
        float y = fminf(fmaxf(cy + dy, 0.f), (float)(Hl - 1));
        int x0 = (int)floorf(x);
        int y0 = (int)floorf(y);
        int x1 = min(x0 + 1, Wl - 1);
        int y1 = min(y0 + 1, Hl - 1);
        float wxh = x - (float)x0, wxl = (float)x1 - x;  // both 0 at exact upper edge
        float wyh = y - (float)y0, wyl = (float)y1 - y;
        int sx0 = min(max(x0 - ix + 3, 0), 7);
        int sx1 = min(max(x1 - ix + 3, 0), 7);
        int sy0 = min(max(y0 - iy + 3, 0), 7);
        int sy1 = min(max(y1 - iy + 3, 0), 7);
        float v = wxl * wyl * Ds[w][sy0 * 8 + sx0]
                + wxl * wyh * Ds[w][sy1 * 8 + sx0]
                + wxh * wyl * Ds[w][sy0 * 8 + sx1]
                + wxh * wyh * Ds[w][sy1 * 8 + sx1];
        out[(size_t)pt * (NLVL * NK) + w * NK + lane] = v;
    }
}

extern "C" void kernel_launch(void* const* d_in, const int* in_sizes, int n_in,
                              void* d_out, int out_size, void* d_ws, size_t ws_size,
                              hipStream_t stream) {
    const float* fmap1   = (const float*)d_in[0];
    const float* fmap2   = (const float*)d_in[1];
    const float* coords1 = (const float*)d_in[2];
    const float* coords2 = (const float*)d_in[3];
    float* out = (float*)d_out;
    float* ws  = (float*)d_ws;

    // workspace layout (float-slot offsets, all multiples of 4 -> 16B aligned)
    float*         raw1 = ws;                               // 524,288 floats
    unsigned char* f1q  = (unsigned char*)(ws + 524288);    // 2,097,152 B
    float*         fsc  = ws + 1048576;                     // 8,192 floats
    unsigned char* q0   = (unsigned char*)(ws + 1056768);   // 2,097,152 B
    float*         s0   = ws + 1581056;                     // 8,192 floats
    unsigned char* q1   = (unsigned char*)(ws + 1589248);   // 524,288 B
    float*         s1   = ws + 1720320;                     // 2,048 floats
    unsigned char* q2   = (unsigned char*)(ws + 1722368);   // 131,072 B
    float*         s2   = ws + 1755136;                     // 512 floats
    unsigned char* q3   = (unsigned char*)(ws + 1755648);   // 32,768 B
    float*         s3   = ws + 1763840;                     // 128 floats
    // total ~1,764,000 float slots = 6.7 MiB

    pre_kernel<<<4608, 256, 0, stream>>>(fmap1, fmap2, coords1,
                                         f1q, fsc, q0, s0, raw1, q1, s1);
    small_kernel<<<160, 256, 0, stream>>>(raw1, q2, s2, q3, s3);
    corr_kernel<<<NB * NPTS, 256, 0, stream>>>(f1q, fsc, coords2,
                                               q0, s0, q1, s1, q2, s2, q3, s3, out);
}

// Round 10
// 110.672 us; speedup vs baseline: 1.9464x; 1.1996x over previous
//
#include <hip/hip_runtime.h>
#include <math.h>

#define NB   2
#define H0   64
#define W0   64
#define NC   256
#define NPTS 4096
#define NLVL 4
#define NK   49   // (2*3+1)^2

__device__ __forceinline__ float wave_reduce_sum(float v) {
    for (int m = 32; m >= 1; m >>= 1)
        v += __shfl_xor(v, m, 64);
    return v;
}

__device__ __forceinline__ float wave_reduce_max(float v) {
    for (int m = 32; m >= 1; m >>= 1)
        v = fmaxf(v, __shfl_xor(v, m, 64));
    return v;
}

// packed signed-int8 dot4 with int32 accumulate
__device__ __forceinline__ int dot4i(unsigned a, unsigned b, int c) {
#if defined(__has_builtin)
#if __has_builtin(__builtin_amdgcn_sdot4)
    return __builtin_amdgcn_sdot4((int)a, (int)b, c, false);
#else
    c += (((int)(a << 24)) >> 24) * (((int)(b << 24)) >> 24);
    c += (((int)(a << 16)) >> 24) * (((int)(b << 16)) >> 24);
    c += (((int)(a <<  8)) >> 24) * (((int)(b <<  8)) >> 24);
    c += (((int)a) >> 24)         * (((int)b) >> 24);
    return c;
#endif
#else
    c += (((int)(a << 24)) >> 24) * (((int)(b << 24)) >> 24);
    c += (((int)(a << 16)) >> 24) * (((int)(b << 16)) >> 24);
    c += (((int)(a <<  8)) >> 24) * (((int)(b <<  8)) >> 24);
    c += (((int)a) >> 24)         * (((int)b) >> 24);
    return c;
#endif
}

// Quantize a wave-held unit vector (4 comps/lane) to int8 with per-vector
// symmetric scale; store packed dword/lane + scale. dot = (int32) * sa * sb.
__device__ __forceinline__ void quant_store(float nx, float ny, float nz, float nw,
                                            unsigned char* __restrict__ qout,
                                            size_t pixIdx,
                                            float* __restrict__ sout, int lane) {
    float m = fmaxf(fmaxf(fabsf(nx), fabsf(ny)), fmaxf(fabsf(nz), fabsf(nw)));
    float M = wave_reduce_max(m);
    float s = (M > 0.f) ? 127.f / M : 0.f;
    int qx = __float2int_rn(nx * s), qy = __float2int_rn(ny * s);
    int qz = __float2int_rn(nz * s), qw = __float2int_rn(nw * s);
    unsigned p = (qx & 0xff) | ((qy & 0xff) << 8) | ((qz & 0xff) << 16) | ((qw & 0xff) << 24);
    ((unsigned*)(qout + pixIdx * NC))[lane] = p;
    if (lane == 0) sout[pixIdx] = (M > 0.f) ? M / 127.f : 0.f;
}

// jax.image.resize bilinear antialias 2x downsample: separable [1,3,3,1]/8,
// OOB taps dropped + renormalized at edges. One wave per OUTPUT pixel.
__device__ __forceinline__ void down_norm(const float* __restrict__ in,
                                          float* __restrict__ raw_out,
                                          unsigned char* __restrict__ qout,
                                          float* __restrict__ sout,
                                          int Hi, int Wi, int wid, int lane) {
    int Ho = Hi >> 1, Wo = Wi >> 1;
    int b = wid / (Ho * Wo);
    int rem = wid - b * (Ho * Wo);
    int yo = rem / Wo, xo = rem - yo * Wo;
    float wy[4], wx[4]; int ty[4], tx[4];
    float sy = 0.f, sx = 0.f;
    for (int j = 0; j < 4; ++j) {
        float w = (j == 0 || j == 3) ? 1.f : 3.f;
        int yi = 2 * yo - 1 + j;
        float wyj = (yi >= 0 && yi < Hi) ? w : 0.f;
        ty[j] = min(max(yi, 0), Hi - 1); wy[j] = wyj; sy += wyj;
        int xi = 2 * xo - 1 + j;
        float wxj = (xi >= 0 && xi < Wi) ? w : 0.f;
        tx[j] = min(max(xi, 0), Wi - 1); wx[j] = wxj; sx += wxj;
    }
    float inv_s = 1.f / (sy * sx);
    float ax = 0.f, ay = 0.f, az = 0.f, aw = 0.f;
    const float4* basep = (const float4*)(in + (size_t)b * Hi * Wi * NC);
    for (int jy = 0; jy < 4; ++jy) {
        if (wy[jy] == 0.f) continue;
        for (int jx = 0; jx < 4; ++jx) {
            float w = wy[jy] * wx[jx];
            if (w == 0.f) continue;
            float4 v = basep[(ty[jy] * Wi + tx[jx]) * (NC / 4) + lane];
            ax += w * v.x; ay += w * v.y; az += w * v.z; aw += w * v.w;
        }
    }
    ax *= inv_s; ay *= inv_s; az *= inv_s; aw *= inv_s;
    float ss = wave_reduce_sum(ax * ax + ay * ay + az * az + aw * aw);
    float inv = 1.f / (sqrtf(ss) + 1e-6f);
    size_t po = (size_t)b * Ho * Wo + (size_t)yo * Wo + xo;
    if (raw_out) {
        float4 r; r.x = ax; r.y = ay; r.z = az; r.w = aw;
        ((float4*)raw_out)[po * (NC / 4) + lane] = r;
    }
    quant_store(ax * inv, ay * inv, az * inv, aw * inv, qout, po, sout, lane);
}

// Fused preprocessing (streaming):
//  [0,2048)    feat1 = normalize(bilinear(fmap1, coords1)) -> int8+scale
//  [2048,4096) level-0 normalize -> int8+scale
//  [4096,4608) level-1 downsample (raw fp32 + int8 norm)
__global__ __launch_bounds__(256)
void pre_kernel(const float* __restrict__ fmap1,
                const float* __restrict__ fmap2,
                const float* __restrict__ coords1,
                unsigned char* __restrict__ f1q, float* __restrict__ fsc,
                unsigned char* __restrict__ q0,  float* __restrict__ s0,
                float* __restrict__ raw1,
                unsigned char* __restrict__ q1,  float* __restrict__ s1) {
    int blk  = blockIdx.x;
    int wv   = threadIdx.x >> 6;
    int lane = threadIdx.x & 63;
    if (blk < 2048) {
        int pt = blk * 4 + wv;
        int b = pt / NPTS;
        float x = coords1[pt * 2 + 0];
        float y = coords1[pt * 2 + 1];
        int x0 = min(max((int)floorf(x), 0), W0 - 1);
        int y0 = min(max((int)floorf(y), 0), H0 - 1);
        int x1 = min(x0 + 1, W0 - 1);
        int y1 = min(y0 + 1, H0 - 1);
        float wxh = x - (float)x0, wxl = (float)x1 - x;   // clip-first semantics
        float wyh = y - (float)y0, wyl = (float)y1 - y;
        float wa = wxl * wyl, wb = wxl * wyh, wc = wxh * wyl, wd = wxh * wyh;
        const float4* base = (const float4*)(fmap1 + (size_t)b * H0 * W0 * NC);
        float4 Ia = base[(y0 * W0 + x0) * (NC / 4) + lane];
        float4 Ib = base[(y1 * W0 + x0) * (NC / 4) + lane];
        float4 Ic = base[(y0 * W0 + x1) * (NC / 4) + lane];
        float4 Id = base[(y1 * W0 + x1) * (NC / 4) + lane];
        float vx = wa * Ia.x + wb * Ib.x + wc * Ic.x + wd * Id.x;
        float vy = wa * Ia.y + wb * Ib.y + wc * Ic.y + wd * Id.y;
        float vz = wa * Ia.z + wb * Ib.z + wc * Ic.z + wd * Id.z;
        float vw = wa * Ia.w + wb * Ib.w + wc * Ic.w + wd * Id.w;
        float ss = wave_reduce_sum(vx * vx + vy * vy + vz * vz + vw * vw);
        float inv = 1.0f / (sqrtf(ss) + 1e-6f);
        quant_store(vx * inv, vy * inv, vz * inv, vw * inv, f1q, pt, fsc, lane);
    } else if (blk < 4096) {
        int p = (blk - 2048) * 4 + wv;
        float4 v = ((const float4*)fmap2)[(size_t)p * (NC / 4) + lane];
        float ss = wave_reduce_sum(v.x * v.x + v.y * v.y + v.z * v.z + v.w * v.w);
        float inv = 1.0f / (sqrtf(ss) + 1e-6f);
        quant_store(v.x * inv, v.y * inv, v.z * inv, v.w * inv, q0, p, s0, lane);
    } else {
        int wid = (blk - 4096) * 4 + wv;
        down_norm(fmap2, raw1, q1, s1, H0, W0, wid, lane);
    }
}

// Small levels from raw1 (cascade), one BLOCK per output pixel for 4x the
// parallelism of R9's one-wave-per-pixel (640 blocks vs 160 — shrinks the
// latency tail). Waves split the tap rows; LDS partial reduce; wave 0 quants.
//  [0,512)   level2: 4x4 taps from raw1 (32x32), wave wv takes row jy==wv
//  [512,640) level3: composed 10x10 taps from raw1, wave wv takes ky%4==wv
__global__ __launch_bounds__(256)
void small_kernel(const float* __restrict__ raw1,
                  unsigned char* __restrict__ q2, float* __restrict__ s2,
                  unsigned char* __restrict__ q3, float* __restrict__ s3) {
    __shared__ float4 part[4][64];
    int blk  = blockIdx.x;
    int wv   = threadIdx.x >> 6;
    int lane = threadIdx.x & 63;
    float ax = 0.f, ay = 0.f, az = 0.f, aw = 0.f;
    unsigned char* qout; float* sout; size_t po;

    if (blk < 512) {
        // level 2: output grid 2x16x16 from raw1 (32x32)
        int b = blk >> 8, rem = blk & 255;
        int yo = rem >> 4, xo = rem & 15;
        float wy[4], wx[4]; int ty[4], tx[4];
        float sy = 0.f, sx = 0.f;
#pragma unroll
        for (int j = 0; j < 4; ++j) {
            float w = (j == 0 || j == 3) ? 1.f : 3.f;
            int yi = 2 * yo - 1 + j;
            float wyj = (yi >= 0 && yi < 32) ? w : 0.f;
            ty[j] = min(max(yi, 0), 31); wy[j] = wyj; sy += wyj;
            int xi = 2 * xo - 1 + j;
            float wxj = (xi >= 0 && xi < 32) ? w : 0.f;
            tx[j] = min(max(xi, 0), 31); wx[j] = wxj; sx += wxj;
        }
        float inv_s = 1.f / (sy * sx);
        const float4* basep = (const float4*)(raw1 + (size_t)b * 32 * 32 * NC);
        int jy = wv;
        if (wy[jy] != 0.f) {
#pragma unroll
            for (int jx = 0; jx < 4; ++jx) {
                float w = wy[jy] * wx[jx] * inv_s;
                if (wx[jx] == 0.f) continue;
                float4 v = basep[(ty[jy] * 32 + tx[jx]) * (NC / 4) + lane];
                ax += w * v.x; ay += w * v.y; az += w * v.z; aw += w * v.w;
            }
        }
        qout = q2; sout = s2; po = (size_t)b * 256 + yo * 16 + xo;
    } else {
        // level 3: output grid 2x8x8, composed 10-tap filter from raw1 (32x32)
        int wid = blk - 512;
        int b = wid >> 6, rem = wid & 63;
        int yo = rem >> 3, xo = rem & 7;
        float Wt[2][10]; int base[2];
        for (int d = 0; d < 2; ++d) {
            int o = d ? xo : yo;
            base[d] = 4 * o - 3;
            float W[10];
            for (int k = 0; k < 10; ++k) W[k] = 0.f;
            float S2 = 0.f;
            for (int j = 0; j < 4; ++j) {
                int yj = 2 * o - 1 + j;
                if (yj < 0 || yj >= 16) continue;
                float wj = (j == 0 || j == 3) ? 1.f : 3.f;
                S2 += wj;
                int yi0 = 2 * yj - 1;
                float wi[4], s1v = 0.f;
                for (int i2 = 0; i2 < 4; ++i2) {
                    int yi = yi0 + i2;
                    wi[i2] = (yi >= 0 && yi < 32) ? ((i2 == 0 || i2 == 3) ? 1.f : 3.f) : 0.f;
                    s1v += wi[i2];
                }
                float sc = wj / s1v;
                for (int i2 = 0; i2 < 4; ++i2)
                    if (wi[i2] > 0.f) W[yi0 + i2 - base[d]] += wi[i2] * sc;
            }
            float invS = 1.f / S2;
            for (int k = 0; k < 10; ++k) Wt[d][k] = W[k] * invS;
        }
        const float4* basep = (const float4*)(raw1 + (size_t)b * 32 * 32 * NC);
        for (int ky = wv; ky < 10; ky += 4) {
            float wyk = Wt[0][ky];
            if (wyk == 0.f) continue;
            int yi = base[0] + ky;
#pragma unroll
            for (int kx = 0; kx < 10; ++kx) {
                float wxk = Wt[1][kx];
                if (wxk == 0.f) continue;
                int xi = base[1] + kx;
                float wgt = wyk * wxk;
                float4 v = basep[(yi * 32 + xi) * (NC / 4) + lane];
                ax += wgt * v.x; ay += wgt * v.y; az += wgt * v.z; aw += wgt * v.w;
            }
        }
        qout = q3; sout = s3; po = (size_t)b * 64 + yo * 8 + xo;
    }

    float4 pr; pr.x = ax; pr.y = ay; pr.z = az; pr.w = aw;
    part[wv][lane] = pr;
    __syncthreads();
    if (wv == 0) {
        float4 p0 = part[0][lane], p1 = part[1][lane];
        float4 p2 = part[2][lane], p3 = part[3][lane];
        ax = p0.x + p1.x + p2.x + p3.x;
        ay = p0.y + p1.y + p2.y + p3.y;
        az = p0.z + p1.z + p2.z + p3.z;
        aw = p0.w + p1.w + p2.w + p3.w;
        float ss = wave_reduce_sum(ax * ax + ay * ay + az * az + aw * aw);
        float inv = 1.f / (sqrtf(ss) + 1e-6f);
        quant_store(ax * inv, ay * inv, az * inv, aw * inv, qout, po, sout, lane);
    }
}

__device__ __forceinline__ int tile_dot(const uint4* buf, const uint4* a4) {
    int ac = 0;
#pragma unroll
    for (int s = 0; s < 4; ++s) {
        uint4 u = buf[s], av = a4[s];
        ac = dot4i(av.x, u.x, ac);
        ac = dot4i(av.y, u.y, ac);
        ac = dot4i(av.z, u.z, ac);
        ac = dot4i(av.w, u.w, ac);
    }
    return ac;
}

// One block per point, wave w = level. int8 pyramid, FULL 4-tile up-front
// prefetch: 16 uint4 px staging (64 VGPRs — half of R5's fp16 version that
// collapsed; R7's 32-VGPR stage survived) + 4 feat1 + 4 scales issued before
// any consumer, then 4 independent int-dot chains. Tell for success:
// VGPR_Count >= ~90.
__global__ __launch_bounds__(256)
void corr_kernel(const unsigned char* __restrict__ f1q,
                 const float* __restrict__ fsc,
                 const float* __restrict__ coords2,
                 const unsigned char* __restrict__ q0, const float* __restrict__ s0,
                 const unsigned char* __restrict__ q1, const float* __restrict__ s1,
                 const unsigned char* __restrict__ q2, const float* __restrict__ s2,
                 const unsigned char* __restrict__ q3, const float* __restrict__ s3,
                 float* __restrict__ out) {
    __shared__ float Ds[NLVL][64];
    int pt = blockIdx.x;
    int b  = pt / NPTS;
    int t  = threadIdx.x;

    int w    = t >> 6;        // level
    int lane = t & 63;
    int Wl = W0 >> w, Hl = H0 >> w;
    float invs = 1.0f / (float)(1 << w);
    float cx = coords2[pt * 2 + 0] * invs;
    float cy = coords2[pt * 2 + 1] * invs;
    int ix = (int)floorf(cx), iy = (int)floorf(cy);

    const unsigned char* f2q = (w == 0) ? q0 : (w == 1) ? q1 : (w == 2) ? q2 : q3;
    const float*         f2s = (w == 0) ? s0 : (w == 1) ? s1 : (w == 2) ? s2 : s3;

    int cg = lane & 3;        // channel chunk group
    int pq = lane >> 2;       // pixel slot (0..15)

    const uint4* pixp[4];
    int pidx[4];
#pragma unroll
    for (int i = 0; i < 4; ++i) {
        int p  = i * 16 + pq;            // grid pixel 0..63
        int jx = p & 7, jy = p >> 3;
        int px = min(max(ix - 3 + jx, 0), Wl - 1);
        int py = min(max(iy - 3 + jy, 0), Hl - 1);
        pidx[i] = (b * Hl + py) * Wl + px;
        pixp[i] = (const uint4*)(f2q + (size_t)pidx[i] * NC);
    }

    // ---- issue ALL loads up front ----
    uint4 bufs[4][4];
#pragma unroll
    for (int i = 0; i < 4; ++i)
#pragma unroll
        for (int s = 0; s < 4; ++s)
            bufs[i][s] = pixp[i][s * 4 + cg];

    const uint4* f1p = (const uint4*)(f1q + (size_t)pt * NC);
    uint4 a4[4];
#pragma unroll
    for (int s = 0; s < 4; ++s) a4[s] = f1p[s * 4 + cg];

    float sb[4];
#pragma unroll
    for (int i = 0; i < 4; ++i) sb[i] = f2s[pidx[i]];
    float sa = fsc[pt];

    // ---- 4 independent dot chains ----
#pragma unroll
    for (int i = 0; i < 4; ++i) {
        int r = tile_dot(bufs[i], a4);
        r += __shfl_xor(r, 1, 64);
        r += __shfl_xor(r, 2, 64);
        if (cg == 0) Ds[w][i * 16 + pq] = (float)r * sa * sb[i];
    }
    __syncthreads();

    if (lane < NK) {
        int tyk = lane / 7, txk = lane % 7;
        float dx = (float)(txk - 3), dy = (float)(tyk - 3);
        float x = fminf(fmaxf(cx + dx, 0.f), (float)(Wl - 1));
        float y = fminf(fmaxf(cy + dy, 0.f), (float)(Hl - 1));
        int x0 = (int)floorf(x);
        int y0 = (int)floorf(y);
        int x1 = min(x0 + 1, Wl - 1);
        int y1 = min(y0 + 1, Hl - 1);
        float wxh = x - (float)x0, wxl = (float)x1 - x;  // both 0 at exact upper edge
        float wyh = y - (float)y0, wyl = (float)y1 - y;
        int sx0 = min(max(x0 - ix + 3, 0), 7);
        int sx1 = min(max(x1 - ix + 3, 0), 7);
        int sy0 = min(max(y0 - iy + 3, 0), 7);
        int sy1 = min(max(y1 - iy + 3, 0), 7);
        float v = wxl * wyl * Ds[w][sy0 * 8 + sx0]
                + wxl * wyh * Ds[w][sy1 * 8 + sx0]
                + wxh * wyl * Ds[w][sy0 * 8 + sx1]
                + wxh * wyh * Ds[w][sy1 * 8 + sx1];
        out[(size_t)pt * (NLVL * NK) + w * NK + lane] = v;
    }
}

extern "C" void kernel_launch(void* const* d_in, const int* in_sizes, int n_in,
                              void* d_out, int out_size, void* d_ws, size_t ws_size,
                              hipStream_t stream) {
    const float* fmap1   = (const float*)d_in[0];
    const float* fmap2   = (const float*)d_in[1];
    const float* coords1 = (const float*)d_in[2];
    const float* coords2 = (const float*)d_in[3];
    float* out = (float*)d_out;
    float* ws  = (float*)d_ws;

    // workspace layout (float-slot offsets, all multiples of 4 -> 16B aligned)
    float*         raw1 = ws;                               // 524,288 floats
    unsigned char* f1q  = (unsigned char*)(ws + 524288);    // 2,097,152 B
    float*         fsc  = ws + 1048576;                     // 8,192 floats
    unsigned char* q0   = (unsigned char*)(ws + 1056768);   // 2,097,152 B
    float*         s0   = ws + 1581056;                     // 8,192 floats
    unsigned char* q1   = (unsigned char*)(ws + 1589248);   // 524,288 B
    float*         s1   = ws + 1720320;                     // 2,048 floats
    unsigned char* q2   = (unsigned char*)(ws + 1722368);   // 131,072 B
    float*         s2   = ws + 1755136;                     // 512 floats
    unsigned char* q3   = (unsigned char*)(ws + 1755648);   // 32,768 B
    float*         s3   = ws + 1763840;                     // 128 floats
    // total ~1,764,000 float slots = 6.7 MiB

    pre_kernel<<<4608, 256, 0, stream>>>(fmap1, fmap2, coords1,
                                         f1q, fsc, q0, s0, raw1, q1, s1);
    small_kernel<<<640, 256, 0, stream>>>(raw1, q2, s2, q3, s3);
    corr_kernel<<<NB * NPTS, 256, 0, stream>>>(f1q, fsc, coords2,
                                               q0, s0, q1, s1, q2, s2, q3, s3, out);
}